// Round 2
// baseline (706.226 us; speedup 1.0000x reference)
//
#include <hip/hip_runtime.h>
#include <hip/hip_bf16.h>

#define BATCH 2
#define SEQLEN 2048
#define DMODEL 256
#define DINNER 512
#define NHEADS 8
#define HEADDIM 64
#define DSTATE 64
#define CONVDIM 640
#define DINPROJ 1160
#define NTOK (BATCH*SEQLEN)

// ---------------- residual copy (fp32 passthrough, float4) ----------------
__global__ void k_residual(const float4* __restrict__ hid, float4* __restrict__ res, int n4){
    int i = blockIdx.x*blockDim.x + threadIdx.x;
    if(i < n4) res[i] = hid[i];
}

// ---------------- LayerNorm + in_proj GEMM ----------------
// 256 blocks x 256 threads; each block: 16 tokens.
__global__ __launch_bounds__(256) void k_ln_inproj(
        const float* __restrict__ hid, const float* __restrict__ nw, const float* __restrict__ nb,
        const float* __restrict__ Win, float* __restrict__ zxbcdt){
    __shared__ float xs[16][DMODEL];
    int t = threadIdx.x;
    int tok0 = blockIdx.x * 16;
    for(int i=0;i<16;i++){
        int idx = i*256 + t;
        int j = idx >> 8, c = idx & 255;
        xs[j][c] = hid[(size_t)(tok0+j)*DMODEL + c];
    }
    __syncthreads();
    int g = t >> 4, il = t & 15;      // group g handles token g (16 lanes each)
    float sum = 0.f, sumsq = 0.f;
    for(int i=0;i<16;i++){ float v = xs[g][il*16+i]; sum += v; sumsq += v*v; }
    #pragma unroll
    for(int m=1;m<16;m<<=1){ sum += __shfl_xor(sum,m); sumsq += __shfl_xor(sumsq,m); }
    float mu   = sum * (1.f/256.f);
    float var  = sumsq*(1.f/256.f) - mu*mu;
    float rstd = rsqrtf(var + 1e-5f);
    for(int i=0;i<16;i++){
        int c = il*16+i;
        xs[g][c] = (xs[g][c]-mu)*rstd*nw[c] + nb[c];
    }
    __syncthreads();
    // x(16x256) @ Win(256x1160)
    for(int cb=0; cb<DINPROJ; cb+=256){
        int col = cb + t;
        if(col < DINPROJ){
            float acc[16];
            #pragma unroll
            for(int j=0;j<16;j++) acc[j]=0.f;
            for(int k=0;k<DMODEL;k+=4){
                float w0 = Win[(size_t)(k+0)*DINPROJ+col];
                float w1 = Win[(size_t)(k+1)*DINPROJ+col];
                float w2 = Win[(size_t)(k+2)*DINPROJ+col];
                float w3 = Win[(size_t)(k+3)*DINPROJ+col];
                #pragma unroll
                for(int j=0;j<16;j++){
                    float4 xv = *(const float4*)&xs[j][k];
                    acc[j] = fmaf(xv.x,w0, fmaf(xv.y,w1, fmaf(xv.z,w2, fmaf(xv.w,w3, acc[j]))));
                }
            }
            for(int j=0;j<16;j++)
                zxbcdt[(size_t)(tok0+j)*DINPROJ + col] = acc[j];
        }
    }
}

// ---------------- causal depthwise conv + SiLU, plus dt/dA ----------------
__global__ __launch_bounds__(256) void k_conv(
        const float* __restrict__ zxbcdt, const float* __restrict__ conv_w, const float* __restrict__ conv_b,
        const float* __restrict__ dt_bias, const float* __restrict__ A_log,
        float* __restrict__ xBC, float* __restrict__ dtw, float* __restrict__ dAw){
    int t = threadIdx.x;
    int c = blockIdx.y*256 + t;
    int tok = blockIdx.x;
    int l = tok & (SEQLEN-1);
    if(c < CONVDIM){
        float4 wv = *(const float4*)&conv_w[c*4];
        float w[4] = {wv.x, wv.y, wv.z, wv.w};
        float acc = conv_b[c];
        #pragma unroll
        for(int k=0;k<4;k++){
            int ls = l + k - 3;
            if(ls >= 0)
                acc += w[k] * zxbcdt[(size_t)(tok-(3-k))*DINPROJ + DINNER + c];
        }
        acc = acc / (1.f + __expf(-acc));       // silu
        xBC[(size_t)tok*CONVDIM + c] = acc;
    } else if(c < CONVDIM + NHEADS){
        int h = c - CONVDIM;
        float v = zxbcdt[(size_t)tok*DINPROJ + (DINPROJ-NHEADS) + h] + dt_bias[h];
        float dt = (v > 20.f) ? v : log1pf(__expf(v));
        float A  = -__expf(A_log[h]);
        dtw[tok*NHEADS+h] = dt;
        dAw[tok*NHEADS+h] = __expf(dt*A);
    }
}

// ---------------- sequential selective scan ----------------
// 64 blocks = (b, h, p-quarter). thread t: p_local = t>>4, owns n in [ (t&15)*4, +4 ).
#define TCH 64
__global__ __launch_bounds__(256) void k_scan(
        const float* __restrict__ xBC, const float* __restrict__ dtw, const float* __restrict__ dAw,
        const float* __restrict__ D_param, float* __restrict__ yw){
    int blk = blockIdx.x;
    int pq = blk & 3, h = (blk>>2)&7, b = blk>>5;
    int t = threadIdx.x;
    int pl = t>>4, ni = t&15;
    int p  = pq*16 + pl;
    __shared__ float Bs[TCH][DSTATE], Cs[TCH][DSTATE], xsv[TCH][16], dts[TCH], dAs[TCH];
    float s0=0.f,s1=0.f,s2=0.f,s3=0.f;
    float Dp = D_param[h];
    const float* base = xBC + (size_t)b*SEQLEN*CONVDIM;
    for(int l0=0; l0<SEQLEN; l0+=TCH){
        __syncthreads();
        for(int i=0;i<16;i++){
            int idx = i*256+t; int st = idx>>6, n = idx&63;
            const float* row = base + (size_t)(l0+st)*CONVDIM;
            Bs[st][n] = row[DINNER + n];
            Cs[st][n] = row[DINNER + DSTATE + n];
        }
        for(int i=0;i<4;i++){
            int idx = i*256+t; int st = idx>>4, pp = idx&15;
            xsv[st][pp] = base[(size_t)(l0+st)*CONVDIM + h*HEADDIM + pq*16 + pp];
        }
        if(t<TCH){
            dts[t] = dtw[((size_t)b*SEQLEN + l0+t)*NHEADS + h];
            dAs[t] = dAw[((size_t)b*SEQLEN + l0+t)*NHEADS + h];
        }
        __syncthreads();
        for(int st=0; st<TCH; st++){
            float dA  = dAs[st];
            float dtx = dts[st]*xsv[st][pl];
            float4 Bv = *(const float4*)&Bs[st][ni*4];
            float4 Cv = *(const float4*)&Cs[st][ni*4];
            s0 = fmaf(s0,dA, dtx*Bv.x);
            s1 = fmaf(s1,dA, dtx*Bv.y);
            s2 = fmaf(s2,dA, dtx*Bv.z);
            s3 = fmaf(s3,dA, dtx*Bv.w);
            float part = fmaf(s0,Cv.x, fmaf(s1,Cv.y, fmaf(s2,Cv.z, s3*Cv.w)));
            part += __shfl_xor(part,1);
            part += __shfl_xor(part,2);
            part += __shfl_xor(part,4);
            part += __shfl_xor(part,8);
            if(ni==0)
                yw[((size_t)b*SEQLEN + l0+st)*DINNER + h*HEADDIM + p] = part + Dp*xsv[st][pl];
        }
    }
}

// ---------------- gate*silu(z) + RMSNorm + out_proj ----------------
__global__ __launch_bounds__(256) void k_out(
        const float* __restrict__ yw, const float* __restrict__ zx, const float* __restrict__ rms_w,
        const float* __restrict__ Wout, float* __restrict__ out){
    __shared__ float gs[16][DINNER];
    int t = threadIdx.x;
    int tok0 = blockIdx.x*16;
    for(int i=0;i<32;i++){
        int idx = i*256+t; int j = idx>>9, c = idx&511;
        float z = zx[(size_t)(tok0+j)*DINPROJ + c];
        float y = yw[(size_t)(tok0+j)*DINNER + c];
        gs[j][c] = y * (z/(1.f+__expf(-z)));
    }
    __syncthreads();
    int g = t>>4, il = t&15;
    float ss = 0.f;
    for(int i=0;i<32;i++){ float v = gs[g][il*32+i]; ss += v*v; }
    #pragma unroll
    for(int m=1;m<16;m<<=1) ss += __shfl_xor(ss,m);
    float sc = rsqrtf(ss*(1.f/512.f) + 1e-5f);
    for(int i=0;i<32;i++){
        int c = il*32+i;
        gs[g][c] *= sc * rms_w[c];
    }
    __syncthreads();
    float acc[16];
    #pragma unroll
    for(int j=0;j<16;j++) acc[j]=0.f;
    for(int k=0;k<DINNER;k+=4){
        float w0 = Wout[(size_t)(k+0)*DMODEL+t];
        float w1 = Wout[(size_t)(k+1)*DMODEL+t];
        float w2 = Wout[(size_t)(k+2)*DMODEL+t];
        float w3 = Wout[(size_t)(k+3)*DMODEL+t];
        #pragma unroll
        for(int j=0;j<16;j++){
            float4 xv = *(const float4*)&gs[j][k];
            acc[j] = fmaf(xv.x,w0, fmaf(xv.y,w1, fmaf(xv.z,w2, fmaf(xv.w,w3, acc[j]))));
        }
    }
    for(int j=0;j<16;j++)
        out[(size_t)(tok0+j)*DMODEL + t] = acc[j];
}

extern "C" void kernel_launch(void* const* d_in, const int* in_sizes, int n_in,
                              void* d_out, int out_size, void* d_ws, size_t ws_size,
                              hipStream_t stream) {
    const float* hid     = (const float*)d_in[0];
    const float* norm_w  = (const float*)d_in[1];
    const float* norm_b  = (const float*)d_in[2];
    const float* Win     = (const float*)d_in[3];
    const float* conv_w  = (const float*)d_in[4];
    const float* conv_b  = (const float*)d_in[5];
    const float* dt_bias = (const float*)d_in[6];
    const float* A_log   = (const float*)d_in[7];
    const float* D_param = (const float*)d_in[8];
    const float* rms_w   = (const float*)d_in[9];
    const float* Wout    = (const float*)d_in[10];

    float* ws = (float*)d_ws;
    float* zxbcdt = ws;                                   // 4096*1160
    float* xBC    = ws + (size_t)NTOK*DINPROJ;            // 4096*640
    float* dtw    = xBC + (size_t)NTOK*CONVDIM;           // 4096*8
    float* dAw    = dtw + (size_t)NTOK*NHEADS;            // 4096*8
    float* yw     = dAw + (size_t)NTOK*NHEADS;            // 4096*512

    float* out = (float*)d_out;
    float* res = out + (size_t)NTOK*DMODEL;

    int n4 = NTOK*DMODEL/4;
    k_residual<<<(n4+255)/256, 256, 0, stream>>>((const float4*)hid, (float4*)res, n4);
    k_ln_inproj<<<NTOK/16, 256, 0, stream>>>(hid, norm_w, norm_b, Win, zxbcdt);
    k_conv<<<dim3(NTOK,3), 256, 0, stream>>>(zxbcdt, conv_w, conv_b, dt_bias, A_log, xBC, dtw, dAw);
    k_scan<<<64, 256, 0, stream>>>(xBC, dtw, dAw, D_param, yw);
    k_out<<<NTOK/16, 256, 0, stream>>>(yw, zxbcdt, rms_w, Wout, out);
}

// Round 3
// 333.223 us; speedup vs baseline: 2.1194x; 2.1194x over previous
//
#include <hip/hip_runtime.h>
#include <hip/hip_bf16.h>

#define BATCH 2
#define SEQLEN 2048
#define DMODEL 256
#define DINNER 512
#define NHEADS 8
#define HEADDIM 64
#define DSTATE 64
#define CONVDIM 640
#define DINPROJ 1160
#define NTOK (BATCH*SEQLEN)
#define Q 64
#define NCH (SEQLEN/Q)   // 32 chunks per batch

// ---------------- residual copy ----------------
__global__ void k_residual(const float4* __restrict__ hid, float4* __restrict__ res, int n4){
    int i = blockIdx.x*blockDim.x + threadIdx.x;
    if(i < n4) res[i] = hid[i];
}

// ---------------- LayerNorm + in_proj GEMM ----------------
__global__ __launch_bounds__(256) void k_ln_inproj(
        const float* __restrict__ hid, const float* __restrict__ nw, const float* __restrict__ nb,
        const float* __restrict__ Win, float* __restrict__ zxbcdt){
    __shared__ float xs[16][DMODEL];
    int t = threadIdx.x;
    int tok0 = blockIdx.x * 16;
    for(int i=0;i<16;i++){
        int idx = i*256 + t;
        int j = idx >> 8, c = idx & 255;
        xs[j][c] = hid[(size_t)(tok0+j)*DMODEL + c];
    }
    __syncthreads();
    int g = t >> 4, il = t & 15;
    float sum = 0.f, sumsq = 0.f;
    for(int i=0;i<16;i++){ float v = xs[g][il*16+i]; sum += v; sumsq += v*v; }
    #pragma unroll
    for(int m=1;m<16;m<<=1){ sum += __shfl_xor(sum,m); sumsq += __shfl_xor(sumsq,m); }
    float mu   = sum * (1.f/256.f);
    float var  = sumsq*(1.f/256.f) - mu*mu;
    float rstd = rsqrtf(var + 1e-5f);
    for(int i=0;i<16;i++){
        int c = il*16+i;
        xs[g][c] = (xs[g][c]-mu)*rstd*nw[c] + nb[c];
    }
    __syncthreads();
    for(int cb=0; cb<DINPROJ; cb+=256){
        int col = cb + t;
        if(col < DINPROJ){
            float acc[16];
            #pragma unroll
            for(int j=0;j<16;j++) acc[j]=0.f;
            for(int k=0;k<DMODEL;k+=4){
                float w0 = Win[(size_t)(k+0)*DINPROJ+col];
                float w1 = Win[(size_t)(k+1)*DINPROJ+col];
                float w2 = Win[(size_t)(k+2)*DINPROJ+col];
                float w3 = Win[(size_t)(k+3)*DINPROJ+col];
                #pragma unroll
                for(int j=0;j<16;j++){
                    float4 xv = *(const float4*)&xs[j][k];
                    acc[j] = fmaf(xv.x,w0, fmaf(xv.y,w1, fmaf(xv.z,w2, fmaf(xv.w,w3, acc[j]))));
                }
            }
            for(int j=0;j<16;j++)
                zxbcdt[(size_t)(tok0+j)*DINPROJ + col] = acc[j];
        }
    }
}

// ---------------- causal conv + SiLU; dt (softplus) and ldA = dt*A ----------------
__global__ __launch_bounds__(256) void k_conv(
        const float* __restrict__ zxbcdt, const float* __restrict__ conv_w, const float* __restrict__ conv_b,
        const float* __restrict__ dt_bias, const float* __restrict__ A_log,
        float* __restrict__ xBC, float* __restrict__ dtw, float* __restrict__ ldAw){
    int t = threadIdx.x;
    int c = blockIdx.y*256 + t;
    int tok = blockIdx.x;
    int l = tok & (SEQLEN-1);
    if(c < CONVDIM){
        float4 wv = *(const float4*)&conv_w[c*4];
        float w[4] = {wv.x, wv.y, wv.z, wv.w};
        float acc = conv_b[c];
        #pragma unroll
        for(int k=0;k<4;k++){
            int ls = l + k - 3;
            if(ls >= 0)
                acc += w[k] * zxbcdt[(size_t)(tok-(3-k))*DINPROJ + DINNER + c];
        }
        acc = acc / (1.f + __expf(-acc));
        xBC[(size_t)tok*CONVDIM + c] = acc;
    } else if(c < CONVDIM + NHEADS){
        int h = c - CONVDIM;
        float v = zxbcdt[(size_t)tok*DINPROJ + (DINPROJ-NHEADS) + h] + dt_bias[h];
        float dt = (v > 20.f) ? v : log1pf(__expf(v));
        float A  = -__expf(A_log[h]);
        dtw[tok*NHEADS+h]  = dt;
        ldAw[tok*NHEADS+h] = dt*A;    // log(dA)
    }
}

// ---------------- chunk-local: Y_intra + D*x, chunk-state contribution ----------------
// grid: 512 = b(2) x h(8) x chunk(32); 256 threads.
__global__ __launch_bounds__(256) void k_chunk1(
        const float* __restrict__ xBC, const float* __restrict__ dtw, const float* __restrict__ ldAw,
        const float* __restrict__ D_param,
        float* __restrict__ yw, float* __restrict__ contrib,
        float* __restrict__ Larr, float* __restrict__ decayArr){
    int blk = blockIdx.x;
    int c = blk & 31, h = (blk>>5)&7, b = blk>>8;
    int t = threadIdx.x;
    __shared__ float xs[Q][68], Bs[Q][68], Cs[Q][68];
    __shared__ float Ls[Q], dts[Q], wch[Q];
    int l0 = c*Q;
    int bh = b*NHEADS + h;
    const float* base = xBC + ((size_t)b*SEQLEN + l0)*CONVDIM;
    // stage x, B, C chunks (each 64x64 fp32)
    for(int i=0;i<4;i++){
        int idx = i*256+t;
        int row = idx>>4, q4 = (idx&15)*4;
        const float* rp = base + (size_t)row*CONVDIM;
        *(float4*)&xs[row][q4] = *(const float4*)(rp + h*HEADDIM + q4);
        *(float4*)&Bs[row][q4] = *(const float4*)(rp + DINNER + q4);
        *(float4*)&Cs[row][q4] = *(const float4*)(rp + DINNER + DSTATE + q4);
    }
    if(t < Q) dts[t] = dtw[((size_t)b*SEQLEN + l0+t)*NHEADS + h];
    if(t < 64){
        float v = ldAw[((size_t)b*SEQLEN + l0+t)*NHEADS + h];
        #pragma unroll
        for(int off=1; off<64; off<<=1){
            float u = __shfl_up(v, off);
            if(t >= off) v += u;
        }
        Ls[t] = v;                     // inclusive cumsum of log dA
    }
    __syncthreads();
    float L63 = Ls[Q-1];
    if(t < Q) wch[t] = __expf(L63 - Ls[t]) * dts[t];
    // ---- G = (C B^T) ∘ M  into registers ----
    int gi = t>>2, r = t&3;
    float g[16];
    {
        float Li = Ls[gi];
        #pragma unroll
        for(int jj=0;jj<16;jj++){
            int j = r + 4*jj;
            float acc = 0.f;
            #pragma unroll
            for(int n=0;n<DSTATE;n+=4){
                float4 cv = *(const float4*)&Cs[gi][n];
                float4 bv = *(const float4*)&Bs[j][n];
                acc = fmaf(cv.x,bv.x, fmaf(cv.y,bv.y, fmaf(cv.z,bv.z, fmaf(cv.w,bv.w, acc))));
            }
            g[jj] = (j <= gi) ? acc * __expf(Li - Ls[j]) * dts[j] : 0.f;
        }
    }
    __syncthreads();
    #pragma unroll
    for(int jj=0;jj<16;jj++) Cs[gi][r + 4*jj] = g[jj];   // overwrite Cs with G∘M
    __syncthreads();
    // ---- Y_intra[i][p] = sum_{j<=i} GM[i][j] x[j][p]  (+ D x) ----
    {
        int p0 = r*16;
        float acc[16];
        #pragma unroll
        for(int pp=0;pp<16;pp++) acc[pp]=0.f;
        for(int j=0;j<=gi;j++){
            float m = Cs[gi][j];
            #pragma unroll
            for(int pp=0;pp<16;pp+=4){
                float4 xv = *(const float4*)&xs[j][p0+pp];
                acc[pp]   = fmaf(m, xv.x, acc[pp]);
                acc[pp+1] = fmaf(m, xv.y, acc[pp+1]);
                acc[pp+2] = fmaf(m, xv.z, acc[pp+2]);
                acc[pp+3] = fmaf(m, xv.w, acc[pp+3]);
            }
        }
        float Dp = D_param[h];
        float* yp = yw + ((size_t)b*SEQLEN + l0 + gi)*DINNER + h*HEADDIM + p0;
        #pragma unroll
        for(int pp=0;pp<16;pp++) yp[pp] = acc[pp] + Dp*xs[gi][p0+pp];
    }
    // ---- S_contrib[p][n] = sum_j wch[j] x[j][p] B[j][n] ----
    {
        int p = t>>2, n0 = (t&3)*16;
        float acc[16];
        #pragma unroll
        for(int nn=0;nn<16;nn++) acc[nn]=0.f;
        for(int j=0;j<Q;j++){
            float xw = xs[j][p]*wch[j];
            #pragma unroll
            for(int nn=0;nn<16;nn+=4){
                float4 bv = *(const float4*)&Bs[j][n0+nn];
                acc[nn]   = fmaf(xw, bv.x, acc[nn]);
                acc[nn+1] = fmaf(xw, bv.y, acc[nn+1]);
                acc[nn+2] = fmaf(xw, bv.z, acc[nn+2]);
                acc[nn+3] = fmaf(xw, bv.w, acc[nn+3]);
            }
        }
        float* cp = contrib + (((size_t)bh*NCH + c)*64 + p)*64 + n0;
        #pragma unroll
        for(int nn=0;nn<16;nn+=4)
            *(float4*)(cp+nn) = make_float4(acc[nn],acc[nn+1],acc[nn+2],acc[nn+3]);
    }
    if(t < Q) Larr[((size_t)bh*NCH + c)*Q + t] = Ls[t];
    if(t == 0) decayArr[bh*NCH + c] = __expf(L63);
}

// ---------------- inter-chunk state scan (in-place: contrib -> S_init) ----------------
// grid: 16 = b*h; 256 threads; each thread owns 16 contiguous state elements.
__global__ __launch_bounds__(256) void k_chunk2(float* __restrict__ contrib,
                                                const float* __restrict__ decayArr){
    int bh = blockIdx.x;
    int t = threadIdx.x;
    float s[16];
    #pragma unroll
    for(int e=0;e<16;e++) s[e]=0.f;
    for(int c=0;c<NCH;c++){
        float d = decayArr[bh*NCH + c];
        float* ptr = contrib + ((size_t)bh*NCH + c)*4096 + t*16;
        #pragma unroll
        for(int e=0;e<16;e+=4){
            float4 tmp = *(float4*)(ptr+e);
            *(float4*)(ptr+e) = make_float4(s[e],s[e+1],s[e+2],s[e+3]);  // S_init for chunk c
            s[e]   = fmaf(s[e],  d, tmp.x);
            s[e+1] = fmaf(s[e+1],d, tmp.y);
            s[e+2] = fmaf(s[e+2],d, tmp.z);
            s[e+3] = fmaf(s[e+3],d, tmp.w);
        }
    }
}

// ---------------- inter-chunk output: y += exp(L_i) * S_init^T C_i ----------------
// grid: 512 = b x h x chunk; 256 threads; thread: p = t&63, wave w = t>>6.
__global__ __launch_bounds__(256) void k_chunk3(
        const float* __restrict__ xBC, const float* __restrict__ states,
        const float* __restrict__ Larr, float* __restrict__ yw){
    int blk = blockIdx.x;
    int c = blk & 31, h = (blk>>5)&7, b = blk>>8;
    int t = threadIdx.x;
    int p = t & 63, w = t >> 6;
    int bh = b*NHEADS + h;
    __shared__ float Cs2[Q][68];
    for(int i=0;i<4;i++){
        int idx = i*256+t;
        int row = idx>>4, q4 = (idx&15)*4;
        *(float4*)&Cs2[row][q4] = *(const float4*)(xBC + ((size_t)b*SEQLEN + c*Q + row)*CONVDIM + DINNER + DSTATE + q4);
    }
    float4 sr[16];
    const float* srow = states + (((size_t)bh*NCH + c)*64 + p)*64;
    #pragma unroll
    for(int n4=0;n4<16;n4++) sr[n4] = *(const float4*)(srow + n4*4);
    __syncthreads();
    const float* Lrow = Larr + ((size_t)bh*NCH + c)*Q;
    for(int ii=0; ii<16; ii++){
        int i = ii*4 + w;
        float acc = 0.f;
        #pragma unroll
        for(int n4=0;n4<16;n4++){
            float4 cv = *(const float4*)&Cs2[i][n4*4];
            acc = fmaf(sr[n4].x,cv.x, fmaf(sr[n4].y,cv.y, fmaf(sr[n4].z,cv.z, fmaf(sr[n4].w,cv.w, acc))));
        }
        float sc = __expf(Lrow[i]);
        size_t yi = ((size_t)b*SEQLEN + c*Q + i)*DINNER + h*HEADDIM + p;
        yw[yi] += sc*acc;
    }
}

// ---------------- gate*silu(z) + RMSNorm + out_proj ----------------
__global__ __launch_bounds__(256) void k_out(
        const float* __restrict__ yw, const float* __restrict__ zx, const float* __restrict__ rms_w,
        const float* __restrict__ Wout, float* __restrict__ out){
    __shared__ float gs[16][DINNER];
    int t = threadIdx.x;
    int tok0 = blockIdx.x*16;
    for(int i=0;i<32;i++){
        int idx = i*256+t; int j = idx>>9, c = idx&511;
        float z = zx[(size_t)(tok0+j)*DINPROJ + c];
        float y = yw[(size_t)(tok0+j)*DINNER + c];
        gs[j][c] = y * (z/(1.f+__expf(-z)));
    }
    __syncthreads();
    int g = t>>4, il = t&15;
    float ss = 0.f;
    for(int i=0;i<32;i++){ float v = gs[g][il*32+i]; ss += v*v; }
    #pragma unroll
    for(int m=1;m<16;m<<=1) ss += __shfl_xor(ss,m);
    float sc = rsqrtf(ss*(1.f/512.f) + 1e-5f);
    for(int i=0;i<32;i++){
        int c = il*32+i;
        gs[g][c] *= sc * rms_w[c];
    }
    __syncthreads();
    float acc[16];
    #pragma unroll
    for(int j=0;j<16;j++) acc[j]=0.f;
    for(int k=0;k<DINNER;k+=4){
        float w0 = Wout[(size_t)(k+0)*DMODEL+t];
        float w1 = Wout[(size_t)(k+1)*DMODEL+t];
        float w2 = Wout[(size_t)(k+2)*DMODEL+t];
        float w3 = Wout[(size_t)(k+3)*DMODEL+t];
        #pragma unroll
        for(int j=0;j<16;j++){
            float4 xv = *(const float4*)&gs[j][k];
            acc[j] = fmaf(xv.x,w0, fmaf(xv.y,w1, fmaf(xv.z,w2, fmaf(xv.w,w3, acc[j]))));
        }
    }
    for(int j=0;j<16;j++)
        out[(size_t)(tok0+j)*DMODEL + t] = acc[j];
}

extern "C" void kernel_launch(void* const* d_in, const int* in_sizes, int n_in,
                              void* d_out, int out_size, void* d_ws, size_t ws_size,
                              hipStream_t stream) {
    const float* hid     = (const float*)d_in[0];
    const float* norm_w  = (const float*)d_in[1];
    const float* norm_b  = (const float*)d_in[2];
    const float* Win     = (const float*)d_in[3];
    const float* conv_w  = (const float*)d_in[4];
    const float* conv_b  = (const float*)d_in[5];
    const float* dt_bias = (const float*)d_in[6];
    const float* A_log   = (const float*)d_in[7];
    const float* D_param = (const float*)d_in[8];
    const float* rms_w   = (const float*)d_in[9];
    const float* Wout    = (const float*)d_in[10];

    float* ws = (float*)d_ws;
    float* zxbcdt = ws;                                    // 4096*1160
    float* xBC    = zxbcdt + (size_t)NTOK*DINPROJ;         // 4096*640
    float* dtw    = xBC + (size_t)NTOK*CONVDIM;            // 4096*8
    float* ldAw   = dtw + (size_t)NTOK*NHEADS;             // 4096*8
    float* yw     = ldAw + (size_t)NTOK*NHEADS;            // 4096*512
    float* contrib= yw + (size_t)NTOK*DINNER;              // 16*32*4096
    float* Larr   = contrib + (size_t)BATCH*NHEADS*NCH*HEADDIM*DSTATE; // 16*32*64
    float* decayA = Larr + (size_t)BATCH*NHEADS*NCH*Q;     // 512

    float* out = (float*)d_out;
    float* res = out + (size_t)NTOK*DMODEL;

    int n4 = NTOK*DMODEL/4;
    k_residual<<<(n4+255)/256, 256, 0, stream>>>((const float4*)hid, (float4*)res, n4);
    k_ln_inproj<<<NTOK/16, 256, 0, stream>>>(hid, norm_w, norm_b, Win, zxbcdt);
    k_conv<<<dim3(NTOK,3), 256, 0, stream>>>(zxbcdt, conv_w, conv_b, dt_bias, A_log, xBC, dtw, ldAw);
    k_chunk1<<<BATCH*NHEADS*NCH, 256, 0, stream>>>(xBC, dtw, ldAw, D_param, yw, contrib, Larr, decayA);
    k_chunk2<<<BATCH*NHEADS, 256, 0, stream>>>(contrib, decayA);
    k_chunk3<<<BATCH*NHEADS*NCH, 256, 0, stream>>>(xBC, contrib, Larr, yw);
    k_out<<<NTOK/16, 256, 0, stream>>>(yw, zxbcdt, rms_w, Wout, out);
}

// Round 4
// 202.091 us; speedup vs baseline: 3.4946x; 1.6489x over previous
//
#include <hip/hip_runtime.h>
#include <hip/hip_bf16.h>

#define BATCH 2
#define SEQLEN 2048
#define DMODEL 256
#define DINNER 512
#define NHEADS 8
#define HEADDIM 64
#define DSTATE 64
#define CONVDIM 640
#define DINPROJ 1160
#define NTOK (BATCH*SEQLEN)
#define Q 64
#define NCH (SEQLEN/Q)
#define NPAD_IN 1216   // 19*64, zero-padded transposed W_in

typedef short v8s __attribute__((ext_vector_type(8)));
typedef float v4f __attribute__((ext_vector_type(4)));

__device__ __forceinline__ unsigned short f2bf(float f){
    __hip_bfloat16 h = __float2bfloat16(f);
    return *reinterpret_cast<unsigned short*>(&h);
}

// ---------------- LayerNorm (+ residual copy), bf16 X output ----------------
__global__ __launch_bounds__(256) void k_ln(
        const float* __restrict__ hid, const float* __restrict__ nw, const float* __restrict__ nb,
        float* __restrict__ res, unsigned short* __restrict__ Xb){
    __shared__ float xs[16][DMODEL];
    int t = threadIdx.x, tok0 = blockIdx.x*16;
    for(int i=0;i<16;i++){
        int idx = i*256+t; int j = idx>>8, c = idx&255;
        float v = hid[(size_t)(tok0+j)*DMODEL + c];
        xs[j][c] = v;
        res[(size_t)(tok0+j)*DMODEL + c] = v;
    }
    __syncthreads();
    int g = t>>4, il = t&15;
    float sum=0.f, sumsq=0.f;
    for(int i=0;i<16;i++){ float v = xs[g][il*16+i]; sum += v; sumsq += v*v; }
    #pragma unroll
    for(int m=1;m<16;m<<=1){ sum += __shfl_xor(sum,m); sumsq += __shfl_xor(sumsq,m); }
    float mu   = sum*(1.f/256.f);
    float var  = sumsq*(1.f/256.f) - mu*mu;
    float rstd = rsqrtf(var + 1e-5f);
    for(int i=0;i<16;i++){
        int c = il*16+i;
        xs[g][c] = (xs[g][c]-mu)*rstd*nw[c] + nb[c];
    }
    __syncthreads();
    for(int i=0;i<16;i++){
        int idx = i*256+t; int j = idx>>8, c = idx&255;
        Xb[(size_t)(tok0+j)*DMODEL + c] = f2bf(xs[j][c]);
    }
}

// ---------------- weight convert+transpose to bf16 N x K ----------------
__global__ __launch_bounds__(256) void k_cvt_in(const float* __restrict__ Win, unsigned short* __restrict__ Wt){
    int n0 = blockIdx.x*4;
    int k  = threadIdx.x;   // 0..255 = K
    #pragma unroll
    for(int i=0;i<4;i++){
        int n = n0+i;
        float v = (n < DINPROJ) ? Win[(size_t)k*DINPROJ + n] : 0.f;
        Wt[(size_t)n*DMODEL + k] = f2bf(v);
    }
}
__global__ __launch_bounds__(256) void k_cvt_out(const float* __restrict__ Wout, unsigned short* __restrict__ Wt){
    int n0 = blockIdx.x*4;
    #pragma unroll
    for(int kk=0;kk<2;kk++){
        int k = threadIdx.x + kk*256;  // 0..511 = K
        #pragma unroll
        for(int i=0;i<4;i++){
            int n = n0+i;
            Wt[(size_t)n*DINNER + k] = f2bf(Wout[(size_t)k*DMODEL + n]);
        }
    }
}

// ---------------- MFMA bf16 GEMM: C(MxN,f32) = A(MxK,bf16) @ Bt(NxK,bf16)^T ----------------
// tile 128x64, 256 threads = 4 waves, wave w does rows [w*32, w*32+32)
__global__ __launch_bounds__(256) void k_gemm(
        const unsigned short* __restrict__ A, const unsigned short* __restrict__ Bt,
        float* __restrict__ C, int K, int Ncols){
    __shared__ __align__(16) unsigned short As[128*40];
    __shared__ __align__(16) unsigned short Bs[64*40];
    int t = threadIdx.x;
    int lane = t & 63, w = t >> 6;
    int lanelow = lane & 15, quad = lane >> 4;
    int tok0 = blockIdx.x * 128;
    int n0   = blockIdx.y * 64;
    v4f acc[2][4];
    #pragma unroll
    for(int mi=0;mi<2;mi++)
        #pragma unroll
        for(int ni=0;ni<4;ni++)
            acc[mi][ni] = (v4f){0.f,0.f,0.f,0.f};
    for(int k0=0; k0<K; k0+=32){
        __syncthreads();
        #pragma unroll
        for(int cc=0; cc<2; cc++){
            int c = t + cc*256;
            int row = c>>2, off = c&3;
            uint4 v = *(const uint4*)(A + (size_t)(tok0+row)*K + k0 + off*8);
            *(uint4*)&As[row*40 + off*8] = v;
        }
        {
            int row = t>>2, off = t&3;
            uint4 v = *(const uint4*)(Bt + (size_t)(n0+row)*K + k0 + off*8);
            *(uint4*)&Bs[row*40 + off*8] = v;
        }
        __syncthreads();
        v8s a0 = *(const v8s*)&As[(w*32 +      lanelow)*40 + quad*8];
        v8s a1 = *(const v8s*)&As[(w*32 + 16 + lanelow)*40 + quad*8];
        v8s b[4];
        #pragma unroll
        for(int ni=0;ni<4;ni++)
            b[ni] = *(const v8s*)&Bs[(ni*16 + lanelow)*40 + quad*8];
        #pragma unroll
        for(int ni=0;ni<4;ni++){
            acc[0][ni] = __builtin_amdgcn_mfma_f32_16x16x32_bf16(a0, b[ni], acc[0][ni], 0,0,0);
            acc[1][ni] = __builtin_amdgcn_mfma_f32_16x16x32_bf16(a1, b[ni], acc[1][ni], 0,0,0);
        }
    }
    #pragma unroll
    for(int mi=0;mi<2;mi++){
        #pragma unroll
        for(int ni=0;ni<4;ni++){
            int col = n0 + ni*16 + lanelow;
            if(col < Ncols){
                #pragma unroll
                for(int r=0;r<4;r++){
                    int row = tok0 + w*32 + mi*16 + quad*4 + r;
                    C[(size_t)row*Ncols + col] = acc[mi][ni][r];
                }
            }
        }
    }
}

// ---------------- causal conv + SiLU; dt (softplus) and ldA = dt*A ----------------
__global__ __launch_bounds__(256) void k_conv(
        const float* __restrict__ zxbcdt, const float* __restrict__ conv_w, const float* __restrict__ conv_b,
        const float* __restrict__ dt_bias, const float* __restrict__ A_log,
        float* __restrict__ xBC, float* __restrict__ dtw, float* __restrict__ ldAw){
    int t = threadIdx.x;
    int c = blockIdx.y*256 + t;
    int tok = blockIdx.x;
    int l = tok & (SEQLEN-1);
    if(c < CONVDIM){
        float4 wv = *(const float4*)&conv_w[c*4];
        float w[4] = {wv.x, wv.y, wv.z, wv.w};
        float acc = conv_b[c];
        #pragma unroll
        for(int k=0;k<4;k++){
            int ls = l + k - 3;
            if(ls >= 0)
                acc += w[k] * zxbcdt[(size_t)(tok-(3-k))*DINPROJ + DINNER + c];
        }
        acc = acc / (1.f + __expf(-acc));
        xBC[(size_t)tok*CONVDIM + c] = acc;
    } else if(c < CONVDIM + NHEADS){
        int h = c - CONVDIM;
        float v = zxbcdt[(size_t)tok*DINPROJ + (DINPROJ-NHEADS) + h] + dt_bias[h];
        float dt = (v > 20.f) ? v : log1pf(__expf(v));
        float A  = -__expf(A_log[h]);
        dtw[tok*NHEADS+h]  = dt;
        ldAw[tok*NHEADS+h] = dt*A;
    }
}

// ---------------- chunk-local ----------------
__global__ __launch_bounds__(256) void k_chunk1(
        const float* __restrict__ xBC, const float* __restrict__ dtw, const float* __restrict__ ldAw,
        const float* __restrict__ D_param,
        float* __restrict__ yw, float* __restrict__ contrib,
        float* __restrict__ Larr, float* __restrict__ decayArr){
    int blk = blockIdx.x;
    int c = blk & 31, h = (blk>>5)&7, b = blk>>8;
    int t = threadIdx.x;
    __shared__ float xs[Q][68], Bsh[Q][68], Csh[Q][68];
    __shared__ float Ls[Q], dts[Q], wch[Q];
    int l0 = c*Q;
    int bh = b*NHEADS + h;
    const float* base = xBC + ((size_t)b*SEQLEN + l0)*CONVDIM;
    for(int i=0;i<4;i++){
        int idx = i*256+t;
        int row = idx>>4, q4 = (idx&15)*4;
        const float* rp = base + (size_t)row*CONVDIM;
        *(float4*)&xs[row][q4]  = *(const float4*)(rp + h*HEADDIM + q4);
        *(float4*)&Bsh[row][q4] = *(const float4*)(rp + DINNER + q4);
        *(float4*)&Csh[row][q4] = *(const float4*)(rp + DINNER + DSTATE + q4);
    }
    if(t < Q) dts[t] = dtw[((size_t)b*SEQLEN + l0+t)*NHEADS + h];
    if(t < 64){
        float v = ldAw[((size_t)b*SEQLEN + l0+t)*NHEADS + h];
        #pragma unroll
        for(int off=1; off<64; off<<=1){
            float u = __shfl_up(v, off);
            if(t >= off) v += u;
        }
        Ls[t] = v;
    }
    __syncthreads();
    float L63 = Ls[Q-1];
    if(t < Q) wch[t] = __expf(L63 - Ls[t]) * dts[t];
    int gi = t>>2, r = t&3;
    float g[16];
    {
        float Li = Ls[gi];
        #pragma unroll
        for(int jj=0;jj<16;jj++){
            int j = r + 4*jj;
            float acc = 0.f;
            #pragma unroll
            for(int n=0;n<DSTATE;n+=4){
                float4 cv = *(const float4*)&Csh[gi][n];
                float4 bv = *(const float4*)&Bsh[j][n];
                acc = fmaf(cv.x,bv.x, fmaf(cv.y,bv.y, fmaf(cv.z,bv.z, fmaf(cv.w,bv.w, acc))));
            }
            g[jj] = (j <= gi) ? acc * __expf(Li - Ls[j]) * dts[j] : 0.f;
        }
    }
    __syncthreads();
    #pragma unroll
    for(int jj=0;jj<16;jj++) Csh[gi][r + 4*jj] = g[jj];
    __syncthreads();
    {
        int p0 = r*16;
        float acc[16];
        #pragma unroll
        for(int pp=0;pp<16;pp++) acc[pp]=0.f;
        for(int j=0;j<=gi;j++){
            float m = Csh[gi][j];
            #pragma unroll
            for(int pp=0;pp<16;pp+=4){
                float4 xv = *(const float4*)&xs[j][p0+pp];
                acc[pp]   = fmaf(m, xv.x, acc[pp]);
                acc[pp+1] = fmaf(m, xv.y, acc[pp+1]);
                acc[pp+2] = fmaf(m, xv.z, acc[pp+2]);
                acc[pp+3] = fmaf(m, xv.w, acc[pp+3]);
            }
        }
        float Dp = D_param[h];
        float* yp = yw + ((size_t)b*SEQLEN + l0 + gi)*DINNER + h*HEADDIM + p0;
        #pragma unroll
        for(int pp=0;pp<16;pp++) yp[pp] = acc[pp] + Dp*xs[gi][p0+pp];
    }
    {
        int p = t>>2, n0 = (t&3)*16;
        float acc[16];
        #pragma unroll
        for(int nn=0;nn<16;nn++) acc[nn]=0.f;
        for(int j=0;j<Q;j++){
            float xw = xs[j][p]*wch[j];
            #pragma unroll
            for(int nn=0;nn<16;nn+=4){
                float4 bv = *(const float4*)&Bsh[j][n0+nn];
                acc[nn]   = fmaf(xw, bv.x, acc[nn]);
                acc[nn+1] = fmaf(xw, bv.y, acc[nn+1]);
                acc[nn+2] = fmaf(xw, bv.z, acc[nn+2]);
                acc[nn+3] = fmaf(xw, bv.w, acc[nn+3]);
            }
        }
        float* cp = contrib + (((size_t)bh*NCH + c)*64 + p)*64 + n0;
        #pragma unroll
        for(int nn=0;nn<16;nn+=4)
            *(float4*)(cp+nn) = make_float4(acc[nn],acc[nn+1],acc[nn+2],acc[nn+3]);
    }
    if(t < Q) Larr[((size_t)bh*NCH + c)*Q + t] = Ls[t];
    if(t == 0) decayArr[bh*NCH + c] = __expf(L63);
}

// ---------------- inter-chunk state scan ----------------
__global__ __launch_bounds__(256) void k_chunk2(float* __restrict__ contrib,
                                                const float* __restrict__ decayArr){
    int bh = blockIdx.x;
    int t = threadIdx.x;
    float s[16];
    #pragma unroll
    for(int e=0;e<16;e++) s[e]=0.f;
    for(int c=0;c<NCH;c++){
        float d = decayArr[bh*NCH + c];
        float* ptr = contrib + ((size_t)bh*NCH + c)*4096 + t*16;
        #pragma unroll
        for(int e=0;e<16;e+=4){
            float4 tmp = *(float4*)(ptr+e);
            *(float4*)(ptr+e) = make_float4(s[e],s[e+1],s[e+2],s[e+3]);
            s[e]   = fmaf(s[e],  d, tmp.x);
            s[e+1] = fmaf(s[e+1],d, tmp.y);
            s[e+2] = fmaf(s[e+2],d, tmp.z);
            s[e+3] = fmaf(s[e+3],d, tmp.w);
        }
    }
}

// ---------------- inter-chunk output ----------------
__global__ __launch_bounds__(256) void k_chunk3(
        const float* __restrict__ xBC, const float* __restrict__ states,
        const float* __restrict__ Larr, float* __restrict__ yw){
    int blk = blockIdx.x;
    int c = blk & 31, h = (blk>>5)&7, b = blk>>8;
    int t = threadIdx.x;
    int p = t & 63, w = t >> 6;
    int bh = b*NHEADS + h;
    __shared__ float Cs2[Q][68];
    for(int i=0;i<4;i++){
        int idx = i*256+t;
        int row = idx>>4, q4 = (idx&15)*4;
        *(float4*)&Cs2[row][q4] = *(const float4*)(xBC + ((size_t)b*SEQLEN + c*Q + row)*CONVDIM + DINNER + DSTATE + q4);
    }
    float4 sr[16];
    const float* srow = states + (((size_t)bh*NCH + c)*64 + p)*64;
    #pragma unroll
    for(int n4=0;n4<16;n4++) sr[n4] = *(const float4*)(srow + n4*4);
    __syncthreads();
    const float* Lrow = Larr + ((size_t)bh*NCH + c)*Q;
    for(int ii=0; ii<16; ii++){
        int i = ii*4 + w;
        float acc = 0.f;
        #pragma unroll
        for(int n4=0;n4<16;n4++){
            float4 cv = *(const float4*)&Cs2[i][n4*4];
            acc = fmaf(sr[n4].x,cv.x, fmaf(sr[n4].y,cv.y, fmaf(sr[n4].z,cv.z, fmaf(sr[n4].w,cv.w, acc))));
        }
        float sc = __expf(Lrow[i]);
        size_t yi = ((size_t)b*SEQLEN + c*Q + i)*DINNER + h*HEADDIM + p;
        yw[yi] += sc*acc;
    }
}

// ---------------- gate*silu(z) + RMSNorm -> bf16 G ----------------
__global__ __launch_bounds__(256) void k_gate(
        const float* __restrict__ yw, const float* __restrict__ zx,
        const float* __restrict__ rms_w, unsigned short* __restrict__ Gb){
    __shared__ float gs[16][DINNER];
    int t = threadIdx.x, tok0 = blockIdx.x*16;
    for(int i=0;i<32;i++){
        int idx = i*256+t; int j = idx>>9, c = idx&511;
        float z = zx[(size_t)(tok0+j)*DINPROJ + c];
        float y = yw[(size_t)(tok0+j)*DINNER + c];
        gs[j][c] = y * (z/(1.f+__expf(-z)));
    }
    __syncthreads();
    int g = t>>4, il = t&15;
    float ss = 0.f;
    for(int i=0;i<32;i++){ float v = gs[g][il*32+i]; ss += v*v; }
    #pragma unroll
    for(int m=1;m<16;m<<=1) ss += __shfl_xor(ss,m);
    float sc = rsqrtf(ss*(1.f/512.f) + 1e-5f);
    for(int i=0;i<32;i++){
        int c = il*32+i;
        gs[g][c] *= sc * rms_w[c];
    }
    __syncthreads();
    for(int i=0;i<32;i++){
        int idx = i*256+t; int j = idx>>9, c = idx&511;
        Gb[(size_t)(tok0+j)*DINNER + c] = f2bf(gs[j][c]);
    }
}

extern "C" void kernel_launch(void* const* d_in, const int* in_sizes, int n_in,
                              void* d_out, int out_size, void* d_ws, size_t ws_size,
                              hipStream_t stream) {
    const float* hid     = (const float*)d_in[0];
    const float* norm_w  = (const float*)d_in[1];
    const float* norm_b  = (const float*)d_in[2];
    const float* Win     = (const float*)d_in[3];
    const float* conv_w  = (const float*)d_in[4];
    const float* conv_b  = (const float*)d_in[5];
    const float* dt_bias = (const float*)d_in[6];
    const float* A_log   = (const float*)d_in[7];
    const float* D_param = (const float*)d_in[8];
    const float* rms_w   = (const float*)d_in[9];
    const float* Wout    = (const float*)d_in[10];

    float* ws = (float*)d_ws;
    float* zxbcdt = ws;                                    // 4096*1160
    float* xBC    = zxbcdt + (size_t)NTOK*DINPROJ;         // 4096*640
    float* dtw    = xBC + (size_t)NTOK*CONVDIM;            // 4096*8
    float* ldAw   = dtw + (size_t)NTOK*NHEADS;             // 4096*8
    float* yw     = ldAw + (size_t)NTOK*NHEADS;            // 4096*512
    float* contrib= yw + (size_t)NTOK*DINNER;              // 16*32*4096
    float* Larr   = contrib + (size_t)BATCH*NHEADS*NCH*HEADDIM*DSTATE;
    float* decayA = Larr + (size_t)BATCH*NHEADS*NCH*Q;     // 512
    unsigned short* Xb  = (unsigned short*)(decayA + 512); // 4096*256 bf16
    unsigned short* Gb  = Xb + (size_t)NTOK*DMODEL;        // 4096*512 bf16
    unsigned short* Wti = Gb + (size_t)NTOK*DINNER;        // 1216*256 bf16
    unsigned short* Wto = Wti + (size_t)NPAD_IN*DMODEL;    // 256*512 bf16

    float* out = (float*)d_out;
    float* res = out + (size_t)NTOK*DMODEL;

    k_ln<<<NTOK/16, 256, 0, stream>>>(hid, norm_w, norm_b, res, Xb);
    k_cvt_in<<<NPAD_IN/4, 256, 0, stream>>>(Win, Wti);
    k_cvt_out<<<DMODEL/4, 256, 0, stream>>>(Wout, Wto);
    k_gemm<<<dim3(NTOK/128, NPAD_IN/64), 256, 0, stream>>>(Xb, Wti, zxbcdt, DMODEL, DINPROJ);
    k_conv<<<dim3(NTOK,3), 256, 0, stream>>>(zxbcdt, conv_w, conv_b, dt_bias, A_log, xBC, dtw, ldAw);
    k_chunk1<<<BATCH*NHEADS*NCH, 256, 0, stream>>>(xBC, dtw, ldAw, D_param, yw, contrib, Larr, decayA);
    k_chunk2<<<BATCH*NHEADS, 256, 0, stream>>>(contrib, decayA);
    k_chunk3<<<BATCH*NHEADS*NCH, 256, 0, stream>>>(xBC, contrib, Larr, yw);
    k_gate<<<NTOK/16, 256, 0, stream>>>(yw, zxbcdt, rms_w, Gb);
    k_gemm<<<dim3(NTOK/128, DMODEL/64), 256, 0, stream>>>(Gb, Wto, out, DINNER, DMODEL);
}

// Round 5
// 187.830 us; speedup vs baseline: 3.7599x; 1.0759x over previous
//
#include <hip/hip_runtime.h>
#include <hip/hip_bf16.h>

#define BATCH 2
#define SEQLEN 2048
#define DMODEL 256
#define DINNER 512
#define NHEADS 8
#define HEADDIM 64
#define DSTATE 64
#define CONVDIM 640
#define DINPROJ 1160
#define NTOK (BATCH*SEQLEN)
#define Q 64
#define NCH (SEQLEN/Q)
#define NPAD_IN 1216   // 19*64, zero-padded transposed W_in
#define TS 72          // bf16 LDS tile stride (16B aligned, 2-way banks max)

typedef short v8s __attribute__((ext_vector_type(8)));
typedef float v4f __attribute__((ext_vector_type(4)));

__device__ __forceinline__ unsigned short f2bf(float f){
    __hip_bfloat16 h = __float2bfloat16(f);
    return *reinterpret_cast<unsigned short*>(&h);
}
__device__ __forceinline__ float bf2f(unsigned short u){
    unsigned int x = ((unsigned int)u) << 16;
    return __uint_as_float(x);
}

// ---------------- LayerNorm (+ residual copy), bf16 X output ----------------
__global__ __launch_bounds__(256) void k_ln(
        const float* __restrict__ hid, const float* __restrict__ nw, const float* __restrict__ nb,
        float* __restrict__ res, unsigned short* __restrict__ Xb){
    __shared__ float xs[16][DMODEL];
    int t = threadIdx.x, tok0 = blockIdx.x*16;
    for(int i=0;i<16;i++){
        int idx = i*256+t; int j = idx>>8, c = idx&255;
        float v = hid[(size_t)(tok0+j)*DMODEL + c];
        xs[j][c] = v;
        res[(size_t)(tok0+j)*DMODEL + c] = v;
    }
    __syncthreads();
    int g = t>>4, il = t&15;
    float sum=0.f, sumsq=0.f;
    for(int i=0;i<16;i++){ float v = xs[g][il*16+i]; sum += v; sumsq += v*v; }
    #pragma unroll
    for(int m=1;m<16;m<<=1){ sum += __shfl_xor(sum,m); sumsq += __shfl_xor(sumsq,m); }
    float mu   = sum*(1.f/256.f);
    float var  = sumsq*(1.f/256.f) - mu*mu;
    float rstd = rsqrtf(var + 1e-5f);
    for(int i=0;i<16;i++){
        int c = il*16+i;
        xs[g][c] = (xs[g][c]-mu)*rstd*nw[c] + nb[c];
    }
    __syncthreads();
    for(int i=0;i<16;i++){
        int idx = i*256+t; int j = idx>>8, c = idx&255;
        Xb[(size_t)(tok0+j)*DMODEL + c] = f2bf(xs[j][c]);
    }
}

// ---------------- weight convert+transpose to bf16 N x K (both weights) ----------------
__global__ __launch_bounds__(256) void k_cvt(const float* __restrict__ Win, const float* __restrict__ Wout,
                                             unsigned short* __restrict__ Wti, unsigned short* __restrict__ Wto){
    int bx = blockIdx.x;
    if(bx < NPAD_IN/4){
        int n0 = bx*4, k = threadIdx.x;
        #pragma unroll
        for(int i=0;i<4;i++){
            int n = n0+i;
            float v = (n < DINPROJ) ? Win[(size_t)k*DINPROJ + n] : 0.f;
            Wti[(size_t)n*DMODEL + k] = f2bf(v);
        }
    } else {
        int n0 = (bx - NPAD_IN/4)*4;
        #pragma unroll
        for(int kk=0;kk<2;kk++){
            int k = threadIdx.x + kk*256;
            #pragma unroll
            for(int i=0;i<4;i++){
                int n = n0+i;
                Wto[(size_t)n*DINNER + k] = f2bf(Wout[(size_t)k*DMODEL + n]);
            }
        }
    }
}

// ---------------- MFMA bf16 GEMM: C(MxN,f32) = A(MxK,bf16) @ Bt(NxK,bf16)^T ----------------
__global__ __launch_bounds__(256) void k_gemm(
        const unsigned short* __restrict__ A, const unsigned short* __restrict__ Bt,
        float* __restrict__ C, int K, int Ncols){
    __shared__ __align__(16) unsigned short As[128*40];
    __shared__ __align__(16) unsigned short Bs[64*40];
    int t = threadIdx.x;
    int lane = t & 63, w = t >> 6;
    int lanelow = lane & 15, quad = lane >> 4;
    int tok0 = blockIdx.x * 128;
    int n0   = blockIdx.y * 64;
    v4f acc[2][4];
    #pragma unroll
    for(int mi=0;mi<2;mi++)
        #pragma unroll
        for(int ni=0;ni<4;ni++)
            acc[mi][ni] = (v4f){0.f,0.f,0.f,0.f};
    for(int k0=0; k0<K; k0+=32){
        __syncthreads();
        #pragma unroll
        for(int cc=0; cc<2; cc++){
            int c = t + cc*256;
            int row = c>>2, off = c&3;
            uint4 v = *(const uint4*)(A + (size_t)(tok0+row)*K + k0 + off*8);
            *(uint4*)&As[row*40 + off*8] = v;
        }
        {
            int row = t>>2, off = t&3;
            uint4 v = *(const uint4*)(Bt + (size_t)(n0+row)*K + k0 + off*8);
            *(uint4*)&Bs[row*40 + off*8] = v;
        }
        __syncthreads();
        v8s a0 = *(const v8s*)&As[(w*32 +      lanelow)*40 + quad*8];
        v8s a1 = *(const v8s*)&As[(w*32 + 16 + lanelow)*40 + quad*8];
        v8s b[4];
        #pragma unroll
        for(int ni=0;ni<4;ni++)
            b[ni] = *(const v8s*)&Bs[(ni*16 + lanelow)*40 + quad*8];
        #pragma unroll
        for(int ni=0;ni<4;ni++){
            acc[0][ni] = __builtin_amdgcn_mfma_f32_16x16x32_bf16(a0, b[ni], acc[0][ni], 0,0,0);
            acc[1][ni] = __builtin_amdgcn_mfma_f32_16x16x32_bf16(a1, b[ni], acc[1][ni], 0,0,0);
        }
    }
    #pragma unroll
    for(int mi=0;mi<2;mi++){
        #pragma unroll
        for(int ni=0;ni<4;ni++){
            int col = n0 + ni*16 + lanelow;
            if(col < Ncols){
                #pragma unroll
                for(int r=0;r<4;r++){
                    int row = tok0 + w*32 + mi*16 + quad*4 + r;
                    C[(size_t)row*Ncols + col] = acc[mi][ni][r];
                }
            }
        }
    }
}

// ---------------- causal conv + SiLU; dt (softplus) and ldA = dt*A ----------------
__global__ __launch_bounds__(256) void k_conv(
        const float* __restrict__ zxbcdt, const float* __restrict__ conv_w, const float* __restrict__ conv_b,
        const float* __restrict__ dt_bias, const float* __restrict__ A_log,
        float* __restrict__ xBC, float* __restrict__ dtw, float* __restrict__ ldAw){
    int t = threadIdx.x;
    int c = blockIdx.y*256 + t;
    int tok = blockIdx.x;
    int l = tok & (SEQLEN-1);
    if(c < CONVDIM){
        float4 wv = *(const float4*)&conv_w[c*4];
        float w[4] = {wv.x, wv.y, wv.z, wv.w};
        float acc = conv_b[c];
        #pragma unroll
        for(int k=0;k<4;k++){
            int ls = l + k - 3;
            if(ls >= 0)
                acc += w[k] * zxbcdt[(size_t)(tok-(3-k))*DINPROJ + DINNER + c];
        }
        acc = acc / (1.f + __expf(-acc));
        xBC[(size_t)tok*CONVDIM + c] = acc;
    } else if(c < CONVDIM + NHEADS){
        int h = c - CONVDIM;
        float v = zxbcdt[(size_t)tok*DINPROJ + (DINPROJ-NHEADS) + h] + dt_bias[h];
        float dt = (v > 20.f) ? v : log1pf(__expf(v));
        float A  = -__expf(A_log[h]);
        dtw[tok*NHEADS+h]  = dt;
        ldAw[tok*NHEADS+h] = dt*A;
    }
}

// ---------------- chunk-local via MFMA ----------------
// grid 512 = b x h x chunk; 256 threads = 4 waves.
// G = (C.B^T) masked/scaled; Y_intra = G.X + D*x ; S_contrib = (w*B)^T . X
__global__ __launch_bounds__(256) void k_chunk1(
        const float* __restrict__ xBC, const float* __restrict__ dtw, const float* __restrict__ ldAw,
        const float* __restrict__ D_param,
        float* __restrict__ yw, float* __restrict__ contrib,
        float* __restrict__ Larr, float* __restrict__ decayArr){
    int blk = blockIdx.x;
    int c = blk & 31, h = (blk>>5)&7, b = blk>>8;
    int t = threadIdx.x;
    int lane = t & 63, w = t >> 6;
    int lanelow = lane & 15, quad = lane >> 4;
    __shared__ __align__(16) unsigned short Cb[64*TS];   // C row-major [i][n]
    __shared__ __align__(16) unsigned short Bb[64*TS];   // B row-major [j][n]
    __shared__ __align__(16) unsigned short BtW[64*TS];  // [n][j] = B[j][n]*wch[j]
    __shared__ __align__(16) unsigned short Xt[64*TS];   // [p][j] = x[j][p]
    __shared__ __align__(16) unsigned short Gb[64*TS];   // masked G row-major [i][j]
    __shared__ float Ls[Q], dts[Q], wch[Q];
    int l0 = c*Q;
    int bh = b*NHEADS + h;
    const float* base = xBC + ((size_t)b*SEQLEN + l0)*CONVDIM;
    // global loads first (hide latency)
    float4 xv[4], bv[4], cv[4];
    int row_[4], q4_[4];
    #pragma unroll
    for(int i=0;i<4;i++){
        int idx = i*256+t;
        int row = idx>>4, q4 = (idx&15)*4;
        row_[i]=row; q4_[i]=q4;
        const float* rp = base + (size_t)row*CONVDIM;
        xv[i] = *(const float4*)(rp + h*HEADDIM + q4);
        bv[i] = *(const float4*)(rp + DINNER + q4);
        cv[i] = *(const float4*)(rp + DINNER + DSTATE + q4);
    }
    float dt_t = 0.f;
    if(t < Q){
        dt_t = dtw[((size_t)b*SEQLEN + l0+t)*NHEADS + h];
        float v = ldAw[((size_t)b*SEQLEN + l0+t)*NHEADS + h];
        #pragma unroll
        for(int off=1; off<64; off<<=1){
            float u = __shfl_up(v, off);
            if(lane >= off) v += u;
        }
        Ls[t]  = v;
        dts[t] = dt_t;
    }
    __syncthreads();
    float L63 = Ls[Q-1];
    if(t < Q) wch[t] = __expf(L63 - Ls[t]) * dt_t;
    __syncthreads();
    // stage bf16 tiles
    #pragma unroll
    for(int i=0;i<4;i++){
        int row = row_[i], q4 = q4_[i];
        float wr = wch[row];
        ushort4 c4; c4.x=f2bf(cv[i].x); c4.y=f2bf(cv[i].y); c4.z=f2bf(cv[i].z); c4.w=f2bf(cv[i].w);
        *(ushort4*)&Cb[row*TS + q4] = c4;
        ushort4 b4; b4.x=f2bf(bv[i].x); b4.y=f2bf(bv[i].y); b4.z=f2bf(bv[i].z); b4.w=f2bf(bv[i].w);
        *(ushort4*)&Bb[row*TS + q4] = b4;
        BtW[(q4+0)*TS + row] = f2bf(bv[i].x * wr);
        BtW[(q4+1)*TS + row] = f2bf(bv[i].y * wr);
        BtW[(q4+2)*TS + row] = f2bf(bv[i].z * wr);
        BtW[(q4+3)*TS + row] = f2bf(bv[i].w * wr);
        Xt[(q4+0)*TS + row] = f2bf(xv[i].x);
        Xt[(q4+1)*TS + row] = f2bf(xv[i].y);
        Xt[(q4+2)*TS + row] = f2bf(xv[i].z);
        Xt[(q4+3)*TS + row] = f2bf(xv[i].w);
    }
    __syncthreads();
    // ---- G = C.B^T (wave w: rows w*16..+16, all 4 col tiles) ----
    v4f g[4];
    #pragma unroll
    for(int nt=0;nt<4;nt++) g[nt] = (v4f){0.f,0.f,0.f,0.f};
    #pragma unroll
    for(int kk=0;kk<2;kk++){
        v8s a = *(const v8s*)&Cb[(w*16+lanelow)*TS + kk*32 + quad*8];
        #pragma unroll
        for(int nt=0;nt<4;nt++){
            v8s bb = *(const v8s*)&Bb[(nt*16+lanelow)*TS + kk*32 + quad*8];
            g[nt] = __builtin_amdgcn_mfma_f32_16x16x32_bf16(a, bb, g[nt], 0,0,0);
        }
    }
    // mask + decay scale, write Gb (A-layout = row-major)
    float Lrow[4];
    #pragma unroll
    for(int r=0;r<4;r++) Lrow[r] = Ls[w*16 + quad*4 + r];
    #pragma unroll
    for(int nt=0;nt<4;nt++){
        int col = nt*16 + lanelow;
        float Lc = Ls[col], dtc = dts[col];
        #pragma unroll
        for(int r=0;r<4;r++){
            int rowg = w*16 + quad*4 + r;
            float val = (col <= rowg) ? g[nt][r] * __expf(Lrow[r]-Lc) * dtc : 0.f;
            Gb[rowg*TS + col] = f2bf(val);
        }
    }
    __syncthreads();
    // ---- Y = G.X ; S = (X^T as A).(BtW as B) ----
    v4f ya[4], sa[4];
    #pragma unroll
    for(int nt=0;nt<4;nt++){ ya[nt]=(v4f){0.f,0.f,0.f,0.f}; sa[nt]=(v4f){0.f,0.f,0.f,0.f}; }
    #pragma unroll
    for(int kk=0;kk<2;kk++){
        v8s ag = *(const v8s*)&Gb[(w*16+lanelow)*TS + kk*32 + quad*8];
        v8s ax = *(const v8s*)&Xt[(w*16+lanelow)*TS + kk*32 + quad*8];
        #pragma unroll
        for(int nt=0;nt<4;nt++){
            v8s bx = *(const v8s*)&Xt[(nt*16+lanelow)*TS + kk*32 + quad*8];
            v8s bw = *(const v8s*)&BtW[(nt*16+lanelow)*TS + kk*32 + quad*8];
            ya[nt] = __builtin_amdgcn_mfma_f32_16x16x32_bf16(ag, bx, ya[nt], 0,0,0);
            sa[nt] = __builtin_amdgcn_mfma_f32_16x16x32_bf16(ax, bw, sa[nt], 0,0,0);
        }
    }
    float Dp = D_param[h];
    #pragma unroll
    for(int nt=0;nt<4;nt++){
        int col = nt*16 + lanelow;
        #pragma unroll
        for(int r=0;r<4;r++){
            int i = w*16 + quad*4 + r;
            float xval = bf2f(Xt[col*TS + i]);   // x[i][p=col]
            yw[((size_t)b*SEQLEN + l0 + i)*DINNER + h*HEADDIM + col] = ya[nt][r] + Dp*xval;
            contrib[(((size_t)bh*NCH + c)*64 + i)*64 + col] = sa[nt][r];  // [p=i][n=col]
        }
    }
    if(t < Q) Larr[((size_t)bh*NCH + c)*Q + t] = Ls[t];
    if(t == 0) decayArr[bh*NCH + c] = __expf(L63);
}

// ---------------- inter-chunk state scan ----------------
__global__ __launch_bounds__(256) void k_chunk2(float* __restrict__ contrib,
                                                const float* __restrict__ decayArr){
    int bh = blockIdx.x;
    int t = threadIdx.x;
    float s[16];
    #pragma unroll
    for(int e=0;e<16;e++) s[e]=0.f;
    for(int c=0;c<NCH;c++){
        float d = decayArr[bh*NCH + c];
        float* ptr = contrib + ((size_t)bh*NCH + c)*4096 + t*16;
        #pragma unroll
        for(int e=0;e<16;e+=4){
            float4 tmp = *(float4*)(ptr+e);
            *(float4*)(ptr+e) = make_float4(s[e],s[e+1],s[e+2],s[e+3]);
            s[e]   = fmaf(s[e],  d, tmp.x);
            s[e+1] = fmaf(s[e+1],d, tmp.y);
            s[e+2] = fmaf(s[e+2],d, tmp.z);
            s[e+3] = fmaf(s[e+3],d, tmp.w);
        }
    }
}

// ---------------- inter-chunk output: y += exp(L_i) * S_init^T C_i ----------------
__global__ __launch_bounds__(256) void k_chunk3(
        const float* __restrict__ xBC, const float* __restrict__ states,
        const float* __restrict__ Larr, float* __restrict__ yw){
    int blk = blockIdx.x;
    int c = blk & 31, h = (blk>>5)&7, b = blk>>8;
    int t = threadIdx.x;
    int p = t & 63, w = t >> 6;
    int bh = b*NHEADS + h;
    __shared__ float Cs2[Q][68];
    for(int i=0;i<4;i++){
        int idx = i*256+t;
        int row = idx>>4, q4 = (idx&15)*4;
        *(float4*)&Cs2[row][q4] = *(const float4*)(xBC + ((size_t)b*SEQLEN + c*Q + row)*CONVDIM + DINNER + DSTATE + q4);
    }
    float4 sr[16];
    const float* srow = states + (((size_t)bh*NCH + c)*64 + p)*64;
    #pragma unroll
    for(int n4=0;n4<16;n4++) sr[n4] = *(const float4*)(srow + n4*4);
    __syncthreads();
    const float* Lrow = Larr + ((size_t)bh*NCH + c)*Q;
    for(int ii=0; ii<16; ii++){
        int i = ii*4 + w;
        float acc = 0.f;
        #pragma unroll
        for(int n4=0;n4<16;n4++){
            float4 cvv = *(const float4*)&Cs2[i][n4*4];
            acc = fmaf(sr[n4].x,cvv.x, fmaf(sr[n4].y,cvv.y, fmaf(sr[n4].z,cvv.z, fmaf(sr[n4].w,cvv.w, acc))));
        }
        float sc = __expf(Lrow[i]);
        size_t yi = ((size_t)b*SEQLEN + c*Q + i)*DINNER + h*HEADDIM + p;
        yw[yi] += sc*acc;
    }
}

// ---------------- gate*silu(z) + RMSNorm -> bf16 G ----------------
__global__ __launch_bounds__(256) void k_gate(
        const float* __restrict__ yw, const float* __restrict__ zx,
        const float* __restrict__ rms_w, unsigned short* __restrict__ Gb){
    __shared__ float gs[16][DINNER];
    int t = threadIdx.x, tok0 = blockIdx.x*16;
    for(int i=0;i<32;i++){
        int idx = i*256+t; int j = idx>>9, c = idx&511;
        float z = zx[(size_t)(tok0+j)*DINPROJ + c];
        float y = yw[(size_t)(tok0+j)*DINNER + c];
        gs[j][c] = y * (z/(1.f+__expf(-z)));
    }
    __syncthreads();
    int g = t>>4, il = t&15;
    float ss = 0.f;
    for(int i=0;i<32;i++){ float v = gs[g][il*32+i]; ss += v*v; }
    #pragma unroll
    for(int m=1;m<16;m<<=1) ss += __shfl_xor(ss,m);
    float sc = rsqrtf(ss*(1.f/512.f) + 1e-5f);
    for(int i=0;i<32;i++){
        int c = il*32+i;
        gs[g][c] *= sc * rms_w[c];
    }
    __syncthreads();
    for(int i=0;i<32;i++){
        int idx = i*256+t; int j = idx>>9, c = idx&511;
        Gb[(size_t)(tok0+j)*DINNER + c] = f2bf(gs[j][c]);
    }
}

extern "C" void kernel_launch(void* const* d_in, const int* in_sizes, int n_in,
                              void* d_out, int out_size, void* d_ws, size_t ws_size,
                              hipStream_t stream) {
    const float* hid     = (const float*)d_in[0];
    const float* norm_w  = (const float*)d_in[1];
    const float* norm_b  = (const float*)d_in[2];
    const float* Win     = (const float*)d_in[3];
    const float* conv_w  = (const float*)d_in[4];
    const float* conv_b  = (const float*)d_in[5];
    const float* dt_bias = (const float*)d_in[6];
    const float* A_log   = (const float*)d_in[7];
    const float* D_param = (const float*)d_in[8];
    const float* rms_w   = (const float*)d_in[9];
    const float* Wout    = (const float*)d_in[10];

    float* ws = (float*)d_ws;
    float* zxbcdt = ws;                                    // 4096*1160
    float* xBC    = zxbcdt + (size_t)NTOK*DINPROJ;         // 4096*640
    float* dtw    = xBC + (size_t)NTOK*CONVDIM;            // 4096*8
    float* ldAw   = dtw + (size_t)NTOK*NHEADS;             // 4096*8
    float* yw     = ldAw + (size_t)NTOK*NHEADS;            // 4096*512
    float* contrib= yw + (size_t)NTOK*DINNER;              // 16*32*4096
    float* Larr   = contrib + (size_t)BATCH*NHEADS*NCH*HEADDIM*DSTATE;
    float* decayA = Larr + (size_t)BATCH*NHEADS*NCH*Q;     // 512
    unsigned short* Xb  = (unsigned short*)(decayA + 512); // 4096*256 bf16
    unsigned short* Gb  = Xb + (size_t)NTOK*DMODEL;        // 4096*512 bf16
    unsigned short* Wti = Gb + (size_t)NTOK*DINNER;        // 1216*256 bf16
    unsigned short* Wto = Wti + (size_t)NPAD_IN*DMODEL;    // 256*512 bf16

    float* out = (float*)d_out;
    float* res = out + (size_t)NTOK*DMODEL;

    k_ln<<<NTOK/16, 256, 0, stream>>>(hid, norm_w, norm_b, res, Xb);
    k_cvt<<<NPAD_IN/4 + DMODEL/4, 256, 0, stream>>>(Win, Wout, Wti, Wto);
    k_gemm<<<dim3(NTOK/128, NPAD_IN/64), 256, 0, stream>>>(Xb, Wti, zxbcdt, DMODEL, DINPROJ);
    k_conv<<<dim3(NTOK,3), 256, 0, stream>>>(zxbcdt, conv_w, conv_b, dt_bias, A_log, xBC, dtw, ldAw);
    k_chunk1<<<BATCH*NHEADS*NCH, 256, 0, stream>>>(xBC, dtw, ldAw, D_param, yw, contrib, Larr, decayA);
    k_chunk2<<<BATCH*NHEADS, 256, 0, stream>>>(contrib, decayA);
    k_chunk3<<<BATCH*NHEADS*NCH, 256, 0, stream>>>(xBC, contrib, Larr, yw);
    k_gate<<<NTOK/16, 256, 0, stream>>>(yw, zxbcdt, rms_w, Gb);
    k_gemm<<<dim3(NTOK/128, DMODEL/64), 256, 0, stream>>>(Gb, Wto, out, DINNER, DMODEL);
}

// Round 6
// 167.513 us; speedup vs baseline: 4.2159x; 1.1213x over previous
//
#include <hip/hip_runtime.h>
#include <hip/hip_bf16.h>

#define BATCH 2
#define SEQLEN 2048
#define DMODEL 256
#define DINNER 512
#define NHEADS 8
#define HEADDIM 64
#define DSTATE 64
#define CONVDIM 640
#define DINPROJ 1160
#define NTOK (BATCH*SEQLEN)
#define Q 64
#define NCH (SEQLEN/Q)
#define NPAD_IN 1216   // 19*64, zero-padded transposed W_in
#define TS 72          // bf16 MFMA tile stride (multiple of 8 -> 16B-aligned v8s rows)
#define RS 202         // raw conv-stage stride (odd half-stride -> conflict-free strided access)

typedef short v8s __attribute__((ext_vector_type(8)));
typedef float v4f __attribute__((ext_vector_type(4)));

__device__ __forceinline__ unsigned short f2bf(float f){
    __hip_bfloat16 h = __float2bfloat16(f);
    return *reinterpret_cast<unsigned short*>(&h);
}
__device__ __forceinline__ float bf2f(unsigned short u){
    unsigned int x = ((unsigned int)u) << 16;
    return __uint_as_float(x);
}

// ---------------- LayerNorm (+ residual copy), bf16 X output ----------------
__global__ __launch_bounds__(256) void k_ln(
        const float* __restrict__ hid, const float* __restrict__ nw, const float* __restrict__ nb,
        float* __restrict__ res, unsigned short* __restrict__ Xb){
    __shared__ float xs[16][DMODEL];
    int t = threadIdx.x, tok0 = blockIdx.x*16;
    for(int i=0;i<16;i++){
        int idx = i*256+t; int j = idx>>8, c = idx&255;
        float v = hid[(size_t)(tok0+j)*DMODEL + c];
        xs[j][c] = v;
        res[(size_t)(tok0+j)*DMODEL + c] = v;
    }
    __syncthreads();
    int g = t>>4, il = t&15;
    float sum=0.f, sumsq=0.f;
    for(int i=0;i<16;i++){ float v = xs[g][il*16+i]; sum += v; sumsq += v*v; }
    #pragma unroll
    for(int m=1;m<16;m<<=1){ sum += __shfl_xor(sum,m); sumsq += __shfl_xor(sumsq,m); }
    float mu   = sum*(1.f/256.f);
    float var  = sumsq*(1.f/256.f) - mu*mu;
    float rstd = rsqrtf(var + 1e-5f);
    for(int i=0;i<16;i++){
        int c = il*16+i;
        xs[g][c] = (xs[g][c]-mu)*rstd*nw[c] + nb[c];
    }
    __syncthreads();
    for(int i=0;i<16;i++){
        int idx = i*256+t; int j = idx>>8, c = idx&255;
        Xb[(size_t)(tok0+j)*DMODEL + c] = f2bf(xs[j][c]);
    }
}

// ---------------- weight convert+transpose to bf16 N x K (both weights) ----------------
__global__ __launch_bounds__(256) void k_cvt(const float* __restrict__ Win, const float* __restrict__ Wout,
                                             unsigned short* __restrict__ Wti, unsigned short* __restrict__ Wto){
    int bx = blockIdx.x;
    if(bx < NPAD_IN/4){
        int n0 = bx*4, k = threadIdx.x;
        #pragma unroll
        for(int i=0;i<4;i++){
            int n = n0+i;
            float v = (n < DINPROJ) ? Win[(size_t)k*DINPROJ + n] : 0.f;
            Wti[(size_t)n*DMODEL + k] = f2bf(v);
        }
    } else {
        int n0 = (bx - NPAD_IN/4)*4;
        #pragma unroll
        for(int kk=0;kk<2;kk++){
            int k = threadIdx.x + kk*256;
            #pragma unroll
            for(int i=0;i<4;i++){
                int n = n0+i;
                Wto[(size_t)n*DINNER + k] = f2bf(Wout[(size_t)k*DMODEL + n]);
            }
        }
    }
}

// ---------------- MFMA bf16 GEMM: C(MxN,f32) = A(MxK,bf16) @ Bt(NxK,bf16)^T ----------------
__global__ __launch_bounds__(256) void k_gemm(
        const unsigned short* __restrict__ A, const unsigned short* __restrict__ Bt,
        float* __restrict__ C, int K, int Ncols){
    __shared__ __align__(16) unsigned short As[128*40];
    __shared__ __align__(16) unsigned short Bs[64*40];
    int t = threadIdx.x;
    int lane = t & 63, w = t >> 6;
    int lanelow = lane & 15, quad = lane >> 4;
    int tok0 = blockIdx.x * 128;
    int n0   = blockIdx.y * 64;
    v4f acc[2][4];
    #pragma unroll
    for(int mi=0;mi<2;mi++)
        #pragma unroll
        for(int ni=0;ni<4;ni++)
            acc[mi][ni] = (v4f){0.f,0.f,0.f,0.f};
    for(int k0=0; k0<K; k0+=32){
        __syncthreads();
        #pragma unroll
        for(int cc=0; cc<2; cc++){
            int c = t + cc*256;
            int row = c>>2, off = c&3;
            uint4 v = *(const uint4*)(A + (size_t)(tok0+row)*K + k0 + off*8);
            *(uint4*)&As[row*40 + off*8] = v;
        }
        {
            int row = t>>2, off = t&3;
            uint4 v = *(const uint4*)(Bt + (size_t)(n0+row)*K + k0 + off*8);
            *(uint4*)&Bs[row*40 + off*8] = v;
        }
        __syncthreads();
        v8s a0 = *(const v8s*)&As[(w*32 +      lanelow)*40 + quad*8];
        v8s a1 = *(const v8s*)&As[(w*32 + 16 + lanelow)*40 + quad*8];
        v8s b[4];
        #pragma unroll
        for(int ni=0;ni<4;ni++)
            b[ni] = *(const v8s*)&Bs[(ni*16 + lanelow)*40 + quad*8];
        #pragma unroll
        for(int ni=0;ni<4;ni++){
            acc[0][ni] = __builtin_amdgcn_mfma_f32_16x16x32_bf16(a0, b[ni], acc[0][ni], 0,0,0);
            acc[1][ni] = __builtin_amdgcn_mfma_f32_16x16x32_bf16(a1, b[ni], acc[1][ni], 0,0,0);
        }
    }
    #pragma unroll
    for(int mi=0;mi<2;mi++){
        #pragma unroll
        for(int ni=0;ni<4;ni++){
            int col = n0 + ni*16 + lanelow;
            if(col < Ncols){
                #pragma unroll
                for(int r=0;r<4;r++){
                    int row = tok0 + w*32 + mi*16 + quad*4 + r;
                    C[(size_t)row*Ncols + col] = acc[mi][ni][r];
                }
            }
        }
    }
}

// ---------------- fused conv + chunk-local SSD via MFMA ----------------
// grid 512 = b x h x chunk; 256 threads = 4 waves.
__global__ __launch_bounds__(256) void k_chunk1(
        const float* __restrict__ zxbcdt, const float* __restrict__ conv_w, const float* __restrict__ conv_b,
        const float* __restrict__ dt_bias, const float* __restrict__ A_log, const float* __restrict__ D_param,
        float* __restrict__ yw, float* __restrict__ contrib,
        float* __restrict__ Larr, float* __restrict__ decayArr, float* __restrict__ Cconv){
    int blk = blockIdx.x;
    int c = blk & 31, h = (blk>>5)&7, b = blk>>8;
    int t = threadIdx.x;
    int lane = t & 63, w = t >> 6;
    int lanelow = lane & 15, quad = lane >> 4;
    __shared__ __align__(16) unsigned short raw[67*RS];    // conv staging; aliased as Gb later
    __shared__ __align__(16) unsigned short Cb[64*TS];
    __shared__ __align__(16) unsigned short Bb[64*TS];
    __shared__ __align__(16) unsigned short BtW[64*TS];
    __shared__ __align__(16) unsigned short Xt[64*TS];
    __shared__ float Ls[Q], dts[Q], wch[Q];
    unsigned short* Gbuf = raw;   // 64*TS = 4608 shorts <= 67*RS, reused after conv phase
    int l0 = c*Q;
    int bh = b*NHEADS + h;
    const float* zbase = zxbcdt + (size_t)(b*SEQLEN + l0)*DINPROJ;
    // ---- stage raw conv inputs (bf16): rows l0-3..l0+63, 192 channels (x_h | B | C) ----
    for(int i=0;i<13;i++){
        int gidx = t + 256*i;
        if(gidx < 67*48){
            int row = gidx/48, grp = gidx%48;
            int ltok = l0 - 3 + row;   // within-batch token
            int gcol = (grp<16) ? (DINNER + h*HEADDIM + grp*4) : (2*DINNER + (grp-16)*4);
            ushort2 lo, hi;
            if(ltok >= 0){
                float4 v = *(const float4*)(zbase + (ptrdiff_t)(row-3)*DINPROJ + gcol);
                lo.x=f2bf(v.x); lo.y=f2bf(v.y); hi.x=f2bf(v.z); hi.y=f2bf(v.w);
            } else { lo.x=lo.y=hi.x=hi.y=0; }
            int ch = (grp<16) ? grp*4 : 64 + (grp-16)*4;
            unsigned short* dst = &raw[row*RS + ch];
            *(ushort2*)dst = lo; *(ushort2*)(dst+2) = hi;
        }
    }
    // ---- dt softplus + ldA cumsum (wave 0) ----
    if(t < Q){
        float v = zbase[(size_t)t*DINPROJ + (DINPROJ-NHEADS) + h] + dt_bias[h];
        float dt = (v > 20.f) ? v : log1pf(__expf(v));
        float A  = -__expf(A_log[h]);
        float ld = dt*A;
        #pragma unroll
        for(int off=1; off<64; off<<=1){
            float u = __shfl_up(ld, off);
            if(lane >= off) ld += u;
        }
        Ls[t] = ld; dts[t] = dt;
    }
    __syncthreads();
    float L63 = Ls[Q-1];
    if(t < Q) wch[t] = __expf(L63 - Ls[t]) * dts[t];
    __syncthreads();
    // ---- conv(K=4) + SiLU -> MFMA tiles (st-per-lane: transposed writes stride-1) ----
    float* CcP = Cconv + ((size_t)b*NCH + c)*4096;
    for(int i=0;i<12;i++){
        int u = t + 256*i;           // 3072 units = 48 ch-groups x 64 rows
        int st = u & 63, c4 = u >> 6, ch = c4*4;
        float xk[4][4];
        #pragma unroll
        for(int k=0;k<4;k++){
            const unsigned short* rp = &raw[(st+k)*RS + ch];
            ushort2 p0 = *(const ushort2*)rp;
            ushort2 p1 = *(const ushort2*)(rp+2);
            xk[k][0]=bf2f(p0.x); xk[k][1]=bf2f(p0.y); xk[k][2]=bf2f(p1.x); xk[k][3]=bf2f(p1.y);
        }
        float wst = wch[st];
        #pragma unroll
        for(int j=0;j<4;j++){
            int chj = ch+j;
            int cc = (chj<64) ? (h*HEADDIM + chj) : (448 + chj);
            float4 wv = *(const float4*)&conv_w[cc*4];
            float acc = conv_b[cc] + wv.x*xk[0][j] + wv.y*xk[1][j] + wv.z*xk[2][j] + wv.w*xk[3][j];
            float sv = acc/(1.f+__expf(-acc));
            if(chj < 64){
                Xt[chj*TS + st] = f2bf(sv);                 // Xt[p][j=st]
            } else if(chj < 128){
                int n = chj-64;
                Bb[st*TS + n]  = f2bf(sv);                  // B[j=st][n]
                BtW[n*TS + st] = f2bf(sv*wst);              // B[j][n]*wch[j], transposed
            } else {
                int n = chj-128;
                Cb[st*TS + n]  = f2bf(sv);                  // C[i=st][n]
                if(h==0) CcP[st*64 + n] = sv;               // fp32 C for k_chunk3
            }
        }
    }
    __syncthreads();
    // ---- G = C.B^T ----
    v4f g[4];
    #pragma unroll
    for(int nt=0;nt<4;nt++) g[nt] = (v4f){0.f,0.f,0.f,0.f};
    #pragma unroll
    for(int kk=0;kk<2;kk++){
        v8s a = *(const v8s*)&Cb[(w*16+lanelow)*TS + kk*32 + quad*8];
        #pragma unroll
        for(int nt=0;nt<4;nt++){
            v8s bb = *(const v8s*)&Bb[(nt*16+lanelow)*TS + kk*32 + quad*8];
            g[nt] = __builtin_amdgcn_mfma_f32_16x16x32_bf16(a, bb, g[nt], 0,0,0);
        }
    }
    // mask + decay scale, write Gbuf (A-layout = row-major)
    float Lrow[4];
    #pragma unroll
    for(int r=0;r<4;r++) Lrow[r] = Ls[w*16 + quad*4 + r];
    #pragma unroll
    for(int nt=0;nt<4;nt++){
        int col = nt*16 + lanelow;
        float Lc = Ls[col], dtc = dts[col];
        #pragma unroll
        for(int r=0;r<4;r++){
            int rowg = w*16 + quad*4 + r;
            float val = (col <= rowg) ? g[nt][r] * __expf(Lrow[r]-Lc) * dtc : 0.f;
            Gbuf[rowg*TS + col] = f2bf(val);
        }
    }
    __syncthreads();
    // ---- Y = G.X ; S = (X^T).(BtW^T) ----
    v4f ya[4], sa[4];
    #pragma unroll
    for(int nt=0;nt<4;nt++){ ya[nt]=(v4f){0.f,0.f,0.f,0.f}; sa[nt]=(v4f){0.f,0.f,0.f,0.f}; }
    #pragma unroll
    for(int kk=0;kk<2;kk++){
        v8s ag = *(const v8s*)&Gbuf[(w*16+lanelow)*TS + kk*32 + quad*8];
        v8s ax = *(const v8s*)&Xt[(w*16+lanelow)*TS + kk*32 + quad*8];
        #pragma unroll
        for(int nt=0;nt<4;nt++){
            v8s bx = *(const v8s*)&Xt[(nt*16+lanelow)*TS + kk*32 + quad*8];
            v8s bw = *(const v8s*)&BtW[(nt*16+lanelow)*TS + kk*32 + quad*8];
            ya[nt] = __builtin_amdgcn_mfma_f32_16x16x32_bf16(ag, bx, ya[nt], 0,0,0);
            sa[nt] = __builtin_amdgcn_mfma_f32_16x16x32_bf16(ax, bw, sa[nt], 0,0,0);
        }
    }
    float Dp = D_param[h];
    #pragma unroll
    for(int nt=0;nt<4;nt++){
        int col = nt*16 + lanelow;
        #pragma unroll
        for(int r=0;r<4;r++){
            int i = w*16 + quad*4 + r;
            float xval = bf2f(Xt[col*TS + i]);   // x[i][p=col]
            yw[((size_t)b*SEQLEN + l0 + i)*DINNER + h*HEADDIM + col] = ya[nt][r] + Dp*xval;
            contrib[(((size_t)bh*NCH + c)*64 + i)*64 + col] = sa[nt][r];  // [p=i][n=col]
        }
    }
    if(t < Q) Larr[((size_t)bh*NCH + c)*Q + t] = Ls[t];
    if(t == 0) decayArr[bh*NCH + c] = __expf(L63);
}

// ---------------- inter-chunk state scan: fully parallel over (bh, element) ----------------
// grid 256 = bh(16) x part(16); thread owns one of 4096 state elements; 32-chunk chain in regs.
__global__ __launch_bounds__(256) void k_chunk2(float* __restrict__ contrib,
                                                const float* __restrict__ decayArr){
    int bh = blockIdx.x >> 4;
    int part = blockIdx.x & 15;
    int e = part*256 + threadIdx.x;
    const size_t base = (size_t)bh*NCH*4096 + e;
    float vals[NCH];
    #pragma unroll
    for(int c=0;c<NCH;c++) vals[c] = contrib[base + (size_t)c*4096];
    float s = 0.f;
    #pragma unroll
    for(int c=0;c<NCH;c++){
        float d = decayArr[bh*NCH + c];
        contrib[base + (size_t)c*4096] = s;    // S_init for chunk c
        s = fmaf(s, d, vals[c]);
    }
}

// ---------------- inter-chunk output: y += exp(L_i) * S_init^T C_i ----------------
__global__ __launch_bounds__(256) void k_chunk3(
        const float* __restrict__ Cconv, const float* __restrict__ states,
        const float* __restrict__ Larr, float* __restrict__ yw){
    int blk = blockIdx.x;
    int c = blk & 31, h = (blk>>5)&7, b = blk>>8;
    int t = threadIdx.x;
    int p = t & 63, w = t >> 6;
    int bh = b*NHEADS + h;
    __shared__ float Cs2[Q][68];
    for(int i=0;i<4;i++){
        int idx = i*256+t;
        int row = idx>>4, q4 = (idx&15)*4;
        *(float4*)&Cs2[row][q4] = *(const float4*)(Cconv + ((size_t)b*NCH + c)*4096 + row*64 + q4);
    }
    float4 sr[16];
    const float* srow = states + (((size_t)bh*NCH + c)*64 + p)*64;
    #pragma unroll
    for(int n4=0;n4<16;n4++) sr[n4] = *(const float4*)(srow + n4*4);
    __syncthreads();
    const float* Lrow = Larr + ((size_t)bh*NCH + c)*Q;
    for(int ii=0; ii<16; ii++){
        int i = ii*4 + w;
        float acc = 0.f;
        #pragma unroll
        for(int n4=0;n4<16;n4++){
            float4 cvv = *(const float4*)&Cs2[i][n4*4];
            acc = fmaf(sr[n4].x,cvv.x, fmaf(sr[n4].y,cvv.y, fmaf(sr[n4].z,cvv.z, fmaf(sr[n4].w,cvv.w, acc))));
        }
        float sc = __expf(Lrow[i]);
        size_t yi = ((size_t)b*SEQLEN + c*Q + i)*DINNER + h*HEADDIM + p;
        yw[yi] += sc*acc;
    }
}

// ---------------- gate*silu(z) + RMSNorm -> bf16 G ----------------
__global__ __launch_bounds__(256) void k_gate(
        const float* __restrict__ yw, const float* __restrict__ zx,
        const float* __restrict__ rms_w, unsigned short* __restrict__ Gb){
    __shared__ float gs[16][DINNER];
    int t = threadIdx.x, tok0 = blockIdx.x*16;
    for(int i=0;i<32;i++){
        int idx = i*256+t; int j = idx>>9, c = idx&511;
        float z = zx[(size_t)(tok0+j)*DINPROJ + c];
        float y = yw[(size_t)(tok0+j)*DINNER + c];
        gs[j][c] = y * (z/(1.f+__expf(-z)));
    }
    __syncthreads();
    int g = t>>4, il = t&15;
    float ss = 0.f;
    for(int i=0;i<32;i++){ float v = gs[g][il*32+i]; ss += v*v; }
    #pragma unroll
    for(int m=1;m<16;m<<=1) ss += __shfl_xor(ss,m);
    float sc = rsqrtf(ss*(1.f/512.f) + 1e-5f);
    for(int i=0;i<32;i++){
        int c = il*32+i;
        gs[g][c] *= sc * rms_w[c];
    }
    __syncthreads();
    for(int i=0;i<32;i++){
        int idx = i*256+t; int j = idx>>9, c = idx&511;
        Gb[(size_t)(tok0+j)*DINNER + c] = f2bf(gs[j][c]);
    }
}

extern "C" void kernel_launch(void* const* d_in, const int* in_sizes, int n_in,
                              void* d_out, int out_size, void* d_ws, size_t ws_size,
                              hipStream_t stream) {
    const float* hid     = (const float*)d_in[0];
    const float* norm_w  = (const float*)d_in[1];
    const float* norm_b  = (const float*)d_in[2];
    const float* Win     = (const float*)d_in[3];
    const float* conv_w  = (const float*)d_in[4];
    const float* conv_b  = (const float*)d_in[5];
    const float* dt_bias = (const float*)d_in[6];
    const float* A_log   = (const float*)d_in[7];
    const float* D_param = (const float*)d_in[8];
    const float* rms_w   = (const float*)d_in[9];
    const float* Wout    = (const float*)d_in[10];

    float* ws = (float*)d_ws;
    float* zxbcdt = ws;                                    // 4096*1160
    float* yw     = zxbcdt + (size_t)NTOK*DINPROJ;         // 4096*512
    float* contrib= yw + (size_t)NTOK*DINNER;              // 16*32*4096
    float* Larr   = contrib + (size_t)BATCH*NHEADS*NCH*HEADDIM*DSTATE;
    float* decayA = Larr + (size_t)BATCH*NHEADS*NCH*Q;     // 512
    float* Cconv  = decayA + 512;                          // 2*32*4096
    unsigned short* Xb  = (unsigned short*)(Cconv + (size_t)BATCH*NCH*Q*DSTATE);
    unsigned short* Gb  = Xb + (size_t)NTOK*DMODEL;        // 4096*512 bf16
    unsigned short* Wti = Gb + (size_t)NTOK*DINNER;        // 1216*256 bf16
    unsigned short* Wto = Wti + (size_t)NPAD_IN*DMODEL;    // 256*512 bf16

    float* out = (float*)d_out;
    float* res = out + (size_t)NTOK*DMODEL;

    k_ln<<<NTOK/16, 256, 0, stream>>>(hid, norm_w, norm_b, res, Xb);
    k_cvt<<<NPAD_IN/4 + DMODEL/4, 256, 0, stream>>>(Win, Wout, Wti, Wto);
    k_gemm<<<dim3(NTOK/128, NPAD_IN/64), 256, 0, stream>>>(Xb, Wti, zxbcdt, DMODEL, DINPROJ);
    k_chunk1<<<BATCH*NHEADS*NCH, 256, 0, stream>>>(zxbcdt, conv_w, conv_b, dt_bias, A_log, D_param,
                                                   yw, contrib, Larr, decayA, Cconv);
    k_chunk2<<<256, 256, 0, stream>>>(contrib, decayA);
    k_chunk3<<<BATCH*NHEADS*NCH, 256, 0, stream>>>(Cconv, contrib, Larr, yw);
    k_gate<<<NTOK/16, 256, 0, stream>>>(yw, zxbcdt, rms_w, Gb);
    k_gemm<<<dim3(NTOK/128, DMODEL/64), 256, 0, stream>>>(Gb, Wto, out, DINNER, DMODEL);
}

// Round 7
// 150.348 us; speedup vs baseline: 4.6973x; 1.1142x over previous
//
#include <hip/hip_runtime.h>
#include <hip/hip_bf16.h>

#define BATCH 2
#define SEQLEN 2048
#define DMODEL 256
#define DINNER 512
#define NHEADS 8
#define HEADDIM 64
#define DSTATE 64
#define CONVDIM 640
#define DINPROJ 1160
#define NTOK (BATCH*SEQLEN)
#define Q 64
#define NCH (SEQLEN/Q)
#define NPAD_IN 1216   // 19*64, zero-padded transposed W_in
#define TS 72          // bf16 MFMA tile stride
#define RS2 198        // raw conv-stage stride in ushorts (word-stride 99, odd -> conflict-free)

typedef short v8s __attribute__((ext_vector_type(8)));
typedef float v4f __attribute__((ext_vector_type(4)));

__device__ __forceinline__ unsigned short f2bf(float f){
    __hip_bfloat16 h = __float2bfloat16(f);
    return *reinterpret_cast<unsigned short*>(&h);
}
__device__ __forceinline__ float bf2f(unsigned short u){
    unsigned int x = ((unsigned int)u) << 16;
    return __uint_as_float(x);
}

// ---------------- LayerNorm (+ residual copy), bf16 X output ----------------
__global__ __launch_bounds__(256) void k_ln(
        const float* __restrict__ hid, const float* __restrict__ nw, const float* __restrict__ nb,
        float* __restrict__ res, unsigned short* __restrict__ Xb){
    __shared__ float xs[16][DMODEL];
    int t = threadIdx.x, tok0 = blockIdx.x*16;
    for(int i=0;i<16;i++){
        int idx = i*256+t; int j = idx>>8, c = idx&255;
        float v = hid[(size_t)(tok0+j)*DMODEL + c];
        xs[j][c] = v;
        res[(size_t)(tok0+j)*DMODEL + c] = v;
    }
    __syncthreads();
    int g = t>>4, il = t&15;
    float sum=0.f, sumsq=0.f;
    for(int i=0;i<16;i++){ float v = xs[g][il*16+i]; sum += v; sumsq += v*v; }
    #pragma unroll
    for(int m=1;m<16;m<<=1){ sum += __shfl_xor(sum,m); sumsq += __shfl_xor(sumsq,m); }
    float mu   = sum*(1.f/256.f);
    float var  = sumsq*(1.f/256.f) - mu*mu;
    float rstd = rsqrtf(var + 1e-5f);
    for(int i=0;i<16;i++){
        int c = il*16+i;
        xs[g][c] = (xs[g][c]-mu)*rstd*nw[c] + nb[c];
    }
    __syncthreads();
    for(int i=0;i<16;i++){
        int idx = i*256+t; int j = idx>>8, c = idx&255;
        Xb[(size_t)(tok0+j)*DMODEL + c] = f2bf(xs[j][c]);
    }
}

// ---------------- weight convert+transpose to bf16 N x K (both weights) ----------------
__global__ __launch_bounds__(256) void k_cvt(const float* __restrict__ Win, const float* __restrict__ Wout,
                                             unsigned short* __restrict__ Wti, unsigned short* __restrict__ Wto){
    int bx = blockIdx.x;
    if(bx < NPAD_IN/4){
        int n0 = bx*4, k = threadIdx.x;
        #pragma unroll
        for(int i=0;i<4;i++){
            int n = n0+i;
            float v = (n < DINPROJ) ? Win[(size_t)k*DINPROJ + n] : 0.f;
            Wti[(size_t)n*DMODEL + k] = f2bf(v);
        }
    } else {
        int n0 = (bx - NPAD_IN/4)*4;
        #pragma unroll
        for(int kk=0;kk<2;kk++){
            int k = threadIdx.x + kk*256;
            #pragma unroll
            for(int i=0;i<4;i++){
                int n = n0+i;
                Wto[(size_t)n*DINNER + k] = f2bf(Wout[(size_t)k*DMODEL + n]);
            }
        }
    }
}

// ---------------- MFMA bf16 GEMM: C(MxN) = A(MxK,bf16) @ Bt(NxK,bf16)^T ----------------
template<int BF16OUT>
__global__ __launch_bounds__(256) void k_gemm(
        const unsigned short* __restrict__ A, const unsigned short* __restrict__ Bt,
        float* __restrict__ Cf, unsigned short* __restrict__ Cb, int K, int Ncols){
    __shared__ __align__(16) unsigned short As[128*40];
    __shared__ __align__(16) unsigned short Bs[64*40];
    int t = threadIdx.x;
    int lane = t & 63, w = t >> 6;
    int lanelow = lane & 15, quad = lane >> 4;
    int tok0 = blockIdx.x * 128;
    int n0   = blockIdx.y * 64;
    v4f acc[2][4];
    #pragma unroll
    for(int mi=0;mi<2;mi++)
        #pragma unroll
        for(int ni=0;ni<4;ni++)
            acc[mi][ni] = (v4f){0.f,0.f,0.f,0.f};
    for(int k0=0; k0<K; k0+=32){
        __syncthreads();
        #pragma unroll
        for(int cc=0; cc<2; cc++){
            int c = t + cc*256;
            int row = c>>2, off = c&3;
            uint4 v = *(const uint4*)(A + (size_t)(tok0+row)*K + k0 + off*8);
            *(uint4*)&As[row*40 + off*8] = v;
        }
        {
            int row = t>>2, off = t&3;
            uint4 v = *(const uint4*)(Bt + (size_t)(n0+row)*K + k0 + off*8);
            *(uint4*)&Bs[row*40 + off*8] = v;
        }
        __syncthreads();
        v8s a0 = *(const v8s*)&As[(w*32 +      lanelow)*40 + quad*8];
        v8s a1 = *(const v8s*)&As[(w*32 + 16 + lanelow)*40 + quad*8];
        v8s b[4];
        #pragma unroll
        for(int ni=0;ni<4;ni++)
            b[ni] = *(const v8s*)&Bs[(ni*16 + lanelow)*40 + quad*8];
        #pragma unroll
        for(int ni=0;ni<4;ni++){
            acc[0][ni] = __builtin_amdgcn_mfma_f32_16x16x32_bf16(a0, b[ni], acc[0][ni], 0,0,0);
            acc[1][ni] = __builtin_amdgcn_mfma_f32_16x16x32_bf16(a1, b[ni], acc[1][ni], 0,0,0);
        }
    }
    #pragma unroll
    for(int mi=0;mi<2;mi++){
        #pragma unroll
        for(int ni=0;ni<4;ni++){
            int col = n0 + ni*16 + lanelow;
            if(col < Ncols){
                #pragma unroll
                for(int r=0;r<4;r++){
                    int row = tok0 + w*32 + mi*16 + quad*4 + r;
                    if(BF16OUT) Cb[(size_t)row*Ncols + col] = f2bf(acc[mi][ni][r]);
                    else        Cf[(size_t)row*Ncols + col] = acc[mi][ni][r];
                }
            }
        }
    }
}

// ---------------- fused conv + chunk-local SSD via MFMA (bf16 in/out) ----------------
// grid 512 = b x h x chunk; 256 threads = 4 waves.
__global__ __launch_bounds__(256) void k_chunk1(
        const unsigned short* __restrict__ zxb, const float* __restrict__ conv_w, const float* __restrict__ conv_b,
        const float* __restrict__ dt_bias, const float* __restrict__ A_log, const float* __restrict__ D_param,
        unsigned short* __restrict__ yw16, float* __restrict__ contrib,
        float* __restrict__ Larr, float* __restrict__ decayArr, unsigned short* __restrict__ Ccv){
    int blk = blockIdx.x;
    int c = blk & 31, h = (blk>>5)&7, b = blk>>8;
    int t = threadIdx.x;
    int lane = t & 63, w = t >> 6;
    int lanelow = lane & 15, quad = lane >> 4;
    __shared__ __align__(16) unsigned short raw[67*RS2];   // conv staging; aliased as Gbuf later
    __shared__ __align__(16) unsigned short Cb[64*TS];
    __shared__ __align__(16) unsigned short Bb[64*TS];
    __shared__ __align__(16) unsigned short BtW[64*TS];
    __shared__ __align__(16) unsigned short Xt[64*TS];
    __shared__ float Ls[Q], dts[Q], wch[Q];
    unsigned short* Gbuf = raw;   // 64*TS = 4608 <= 67*RS2
    int l0 = c*Q;
    int bh = b*NHEADS + h;
    const unsigned short* zbase = zxb + (size_t)(b*SEQLEN + l0)*DINPROJ;
    // ---- stage raw conv inputs (bf16): rows l0-3..l0+63, 192 ch (x_h | B | C), 8 ch/unit ----
    for(int i=0;i<7;i++){
        int gidx = t + 256*i;
        if(gidx < 67*24){
            int row = gidx/24, g = gidx%24;
            int ltok = l0 - 3 + row;
            int gcol = (g<8) ? (DINNER + h*HEADDIM + g*8) : (2*DINNER + (g-8)*8);
            uint4 v;
            if(ltok >= 0) v = *(const uint4*)(zbase + (ptrdiff_t)(row-3)*DINPROJ + gcol);
            else { v.x=0; v.y=0; v.z=0; v.w=0; }
            int ch = (g<8) ? g*8 : 64 + (g-8)*8;
            unsigned int* d = (unsigned int*)&raw[row*RS2 + ch];  // 4B-aligned (row*RS2, ch even)
            d[0]=v.x; d[1]=v.y; d[2]=v.z; d[3]=v.w;
        }
    }
    // ---- dt softplus + ldA cumsum (wave 0) ----
    if(t < Q){
        float v = bf2f(zbase[(size_t)t*DINPROJ + (DINPROJ-NHEADS) + h]) + dt_bias[h];
        float dt = (v > 20.f) ? v : log1pf(__expf(v));
        float A  = -__expf(A_log[h]);
        float ld = dt*A;
        #pragma unroll
        for(int off=1; off<64; off<<=1){
            float u = __shfl_up(ld, off);
            if(lane >= off) ld += u;
        }
        Ls[t] = ld; dts[t] = dt;
    }
    __syncthreads();
    float L63 = Ls[Q-1];
    if(t < Q) wch[t] = __expf(L63 - Ls[t]) * dts[t];
    __syncthreads();
    // ---- conv(K=4) + SiLU -> MFMA tiles ----
    unsigned short* CcP = Ccv + ((size_t)b*NCH + c)*4096;
    for(int i=0;i<12;i++){
        int u = t + 256*i;           // 3072 units = 48 ch-groups(4ch) x 64 rows
        int st = u & 63, c4 = u >> 6, ch = c4*4;
        float xk[4][4];
        #pragma unroll
        for(int k=0;k<4;k++){
            const unsigned short* rp = &raw[(st+k)*RS2 + ch];
            ushort2 p0 = *(const ushort2*)rp;
            ushort2 p1 = *(const ushort2*)(rp+2);
            xk[k][0]=bf2f(p0.x); xk[k][1]=bf2f(p0.y); xk[k][2]=bf2f(p1.x); xk[k][3]=bf2f(p1.y);
        }
        float wst = wch[st];
        #pragma unroll
        for(int j=0;j<4;j++){
            int chj = ch+j;
            int cc = (chj<64) ? (h*HEADDIM + chj) : (448 + chj);
            float4 wv = *(const float4*)&conv_w[cc*4];
            float acc = conv_b[cc] + wv.x*xk[0][j] + wv.y*xk[1][j] + wv.z*xk[2][j] + wv.w*xk[3][j];
            float sv = acc/(1.f+__expf(-acc));
            if(chj < 64){
                Xt[chj*TS + st] = f2bf(sv);
            } else if(chj < 128){
                int n = chj-64;
                Bb[st*TS + n]  = f2bf(sv);
                BtW[n*TS + st] = f2bf(sv*wst);
            } else {
                int n = chj-128;
                unsigned short sb = f2bf(sv);
                Cb[st*TS + n] = sb;
                if(h==0) CcP[st*64 + n] = sb;
            }
        }
    }
    __syncthreads();
    // ---- G = C.B^T ----
    v4f g[4];
    #pragma unroll
    for(int nt=0;nt<4;nt++) g[nt] = (v4f){0.f,0.f,0.f,0.f};
    #pragma unroll
    for(int kk=0;kk<2;kk++){
        v8s a = *(const v8s*)&Cb[(w*16+lanelow)*TS + kk*32 + quad*8];
        #pragma unroll
        for(int nt=0;nt<4;nt++){
            v8s bb = *(const v8s*)&Bb[(nt*16+lanelow)*TS + kk*32 + quad*8];
            g[nt] = __builtin_amdgcn_mfma_f32_16x16x32_bf16(a, bb, g[nt], 0,0,0);
        }
    }
    float Lrow[4];
    #pragma unroll
    for(int r=0;r<4;r++) Lrow[r] = Ls[w*16 + quad*4 + r];
    #pragma unroll
    for(int nt=0;nt<4;nt++){
        int col = nt*16 + lanelow;
        float Lc = Ls[col], dtc = dts[col];
        #pragma unroll
        for(int r=0;r<4;r++){
            int rowg = w*16 + quad*4 + r;
            float val = (col <= rowg) ? g[nt][r] * __expf(Lrow[r]-Lc) * dtc : 0.f;
            Gbuf[rowg*TS + col] = f2bf(val);
        }
    }
    __syncthreads();
    // ---- Y = G.X ; S = (X^T).(BtW^T) ----
    v4f ya[4], sa[4];
    #pragma unroll
    for(int nt=0;nt<4;nt++){ ya[nt]=(v4f){0.f,0.f,0.f,0.f}; sa[nt]=(v4f){0.f,0.f,0.f,0.f}; }
    #pragma unroll
    for(int kk=0;kk<2;kk++){
        v8s ag = *(const v8s*)&Gbuf[(w*16+lanelow)*TS + kk*32 + quad*8];
        v8s ax = *(const v8s*)&Xt[(w*16+lanelow)*TS + kk*32 + quad*8];
        #pragma unroll
        for(int nt=0;nt<4;nt++){
            v8s bx = *(const v8s*)&Xt[(nt*16+lanelow)*TS + kk*32 + quad*8];
            v8s bw = *(const v8s*)&BtW[(nt*16+lanelow)*TS + kk*32 + quad*8];
            ya[nt] = __builtin_amdgcn_mfma_f32_16x16x32_bf16(ag, bx, ya[nt], 0,0,0);
            sa[nt] = __builtin_amdgcn_mfma_f32_16x16x32_bf16(ax, bw, sa[nt], 0,0,0);
        }
    }
    float Dp = D_param[h];
    #pragma unroll
    for(int nt=0;nt<4;nt++){
        int col = nt*16 + lanelow;
        #pragma unroll
        for(int r=0;r<4;r++){
            int i = w*16 + quad*4 + r;
            float xval = bf2f(Xt[col*TS + i]);
            yw16[((size_t)b*SEQLEN + l0 + i)*DINNER + h*HEADDIM + col] = f2bf(ya[nt][r] + Dp*xval);
            contrib[(((size_t)bh*NCH + c)*64 + i)*64 + col] = sa[nt][r];
        }
    }
    if(t < Q) Larr[((size_t)bh*NCH + c)*Q + t] = Ls[t];
    if(t == 0) decayArr[bh*NCH + c] = __expf(L63);
}

// ---------------- inter-chunk state scan: parallel over (bh, element); bf16 S_init out ----------------
__global__ __launch_bounds__(256) void k_chunk2(const float* __restrict__ contrib,
                                                const float* __restrict__ decayArr,
                                                unsigned short* __restrict__ Sb){
    int bh = blockIdx.x >> 4;
    int part = blockIdx.x & 15;
    int e = part*256 + threadIdx.x;
    const size_t base = (size_t)bh*NCH*4096 + e;
    float vals[NCH];
    #pragma unroll
    for(int c=0;c<NCH;c++) vals[c] = contrib[base + (size_t)c*4096];
    float s = 0.f;
    #pragma unroll
    for(int c=0;c<NCH;c++){
        Sb[base + (size_t)c*4096] = f2bf(s);   // S_init for chunk c
        s = fmaf(s, decayArr[bh*NCH + c], vals[c]);
    }
}

// ---------------- fused inter-chunk output + gate + RMSNorm -> bf16 G ----------------
// grid 64 = b(2) x chunk(32); 512 threads = 8 waves, wave = head.
__global__ __launch_bounds__(512) void k_tail(
        const unsigned short* __restrict__ Ccv, const unsigned short* __restrict__ Sb,
        const float* __restrict__ Larr, const unsigned short* __restrict__ yw16,
        const unsigned short* __restrict__ zxb, const float* __restrict__ rms_w,
        unsigned short* __restrict__ Gb){
    int blk = blockIdx.x;
    int c = blk & 31, b = blk >> 5;
    int t = threadIdx.x;
    int h = t >> 6, lane = t & 63;
    int lanelow = lane & 15, quad = lane >> 4;
    int bh = b*NHEADS + h;
    __shared__ float wsum[8][64];
    __shared__ float rstdS[64];
    const unsigned short* Cp = Ccv + ((size_t)b*NCH + c)*4096;
    const unsigned short* Sp = Sb + ((size_t)bh*NCH + c)*4096;
    // A-frags (C rows), 4 row-tiles x 2 k-halves
    v8s a[4][2];
    #pragma unroll
    for(int rt=0;rt<4;rt++){
        a[rt][0] = *(const v8s*)(Cp + (rt*16+lanelow)*64 + quad*8);
        a[rt][1] = *(const v8s*)(Cp + (rt*16+lanelow)*64 + 32 + quad*8);
    }
    // B-frags (S_init rows = p)
    v8s s[4][2];
    #pragma unroll
    for(int nt=0;nt<4;nt++){
        s[nt][0] = *(const v8s*)(Sp + (nt*16+lanelow)*64 + quad*8);
        s[nt][1] = *(const v8s*)(Sp + (nt*16+lanelow)*64 + 32 + quad*8);
    }
    float g[4][4][4];   // [rt][nt][r]
    float sq[4][4];     // [rt][r]
    const float* Lp = Larr + ((size_t)bh*NCH + c)*Q;
    #pragma unroll
    for(int rt=0;rt<4;rt++){
        float eL[4];
        #pragma unroll
        for(int r=0;r<4;r++) eL[r] = __expf(Lp[rt*16 + quad*4 + r]);
        #pragma unroll
        for(int nt=0;nt<4;nt++){
            v4f acc = (v4f){0.f,0.f,0.f,0.f};
            acc = __builtin_amdgcn_mfma_f32_16x16x32_bf16(a[rt][0], s[nt][0], acc, 0,0,0);
            acc = __builtin_amdgcn_mfma_f32_16x16x32_bf16(a[rt][1], s[nt][1], acc, 0,0,0);
            int col = h*HEADDIM + nt*16 + lanelow;
            #pragma unroll
            for(int r=0;r<4;r++){
                int i = rt*16 + quad*4 + r;
                size_t tok = (size_t)b*SEQLEN + c*Q + i;
                float yv = acc[r]*eL[r] + bf2f(yw16[tok*DINNER + col]);
                float z  = bf2f(zxb[tok*DINPROJ + col]);
                float gg = yv * (z/(1.f+__expf(-z)));
                g[rt][nt][r] = gg;
                sq[rt][r] = (nt==0 ? gg*gg : sq[rt][r] + gg*gg);
            }
        }
    }
    #pragma unroll
    for(int rt=0;rt<4;rt++)
        #pragma unroll
        for(int r=0;r<4;r++){
            float v = sq[rt][r];
            #pragma unroll
            for(int m=1;m<16;m<<=1) v += __shfl_xor(v, m);
            sq[rt][r] = v;
        }
    if(lanelow==0){
        #pragma unroll
        for(int rt=0;rt<4;rt++)
            #pragma unroll
            for(int r=0;r<4;r++)
                wsum[h][rt*16 + quad*4 + r] = sq[rt][r];
    }
    __syncthreads();
    if(t < 64){
        float tot = 0.f;
        #pragma unroll
        for(int hh=0;hh<8;hh++) tot += wsum[hh][t];
        rstdS[t] = rsqrtf(tot*(1.f/512.f) + 1e-5f);
    }
    __syncthreads();
    #pragma unroll
    for(int rt=0;rt<4;rt++){
        #pragma unroll
        for(int nt=0;nt<4;nt++){
            int col = h*HEADDIM + nt*16 + lanelow;
            float rw = rms_w[col];
            #pragma unroll
            for(int r=0;r<4;r++){
                int i = rt*16 + quad*4 + r;
                Gb[((size_t)b*SEQLEN + c*Q + i)*DINNER + col] = f2bf(g[rt][nt][r] * rstdS[i] * rw);
            }
        }
    }
}

extern "C" void kernel_launch(void* const* d_in, const int* in_sizes, int n_in,
                              void* d_out, int out_size, void* d_ws, size_t ws_size,
                              hipStream_t stream) {
    const float* hid     = (const float*)d_in[0];
    const float* norm_w  = (const float*)d_in[1];
    const float* norm_b  = (const float*)d_in[2];
    const float* Win     = (const float*)d_in[3];
    const float* conv_w  = (const float*)d_in[4];
    const float* conv_b  = (const float*)d_in[5];
    const float* dt_bias = (const float*)d_in[6];
    const float* A_log   = (const float*)d_in[7];
    const float* D_param = (const float*)d_in[8];
    const float* rms_w   = (const float*)d_in[9];
    const float* Wout    = (const float*)d_in[10];

    float* ws = (float*)d_ws;
    float* contrib = ws;                                          // 16*32*4096 f
    float* Larr    = contrib + (size_t)16*NCH*4096;               // 32768 f
    float* decayA  = Larr + (size_t)16*NCH*Q;                     // 512 f
    unsigned short* zxb  = (unsigned short*)(decayA + 512);       // 4096*1160
    unsigned short* yw16 = zxb + (size_t)NTOK*DINPROJ;            // 4096*512
    unsigned short* Sb   = yw16 + (size_t)NTOK*DINNER;            // 16*32*4096
    unsigned short* Ccv  = Sb + (size_t)16*NCH*4096;              // 2*32*4096
    unsigned short* Xb   = Ccv + (size_t)BATCH*NCH*4096;          // 4096*256
    unsigned short* Gb   = Xb + (size_t)NTOK*DMODEL;              // 4096*512
    unsigned short* Wti  = Gb + (size_t)NTOK*DINNER;              // 1216*256
    unsigned short* Wto  = Wti + (size_t)NPAD_IN*DMODEL;          // 256*512

    float* out = (float*)d_out;
    float* res = out + (size_t)NTOK*DMODEL;

    k_ln<<<NTOK/16, 256, 0, stream>>>(hid, norm_w, norm_b, res, Xb);
    k_cvt<<<NPAD_IN/4 + DMODEL/4, 256, 0, stream>>>(Win, Wout, Wti, Wto);
    k_gemm<1><<<dim3(NTOK/128, NPAD_IN/64), 256, 0, stream>>>(Xb, Wti, nullptr, zxb, DMODEL, DINPROJ);
    k_chunk1<<<BATCH*NHEADS*NCH, 256, 0, stream>>>(zxb, conv_w, conv_b, dt_bias, A_log, D_param,
                                                   yw16, contrib, Larr, decayA, Ccv);
    k_chunk2<<<256, 256, 0, stream>>>(contrib, decayA, Sb);
    k_tail<<<BATCH*NCH, 512, 0, stream>>>(Ccv, Sb, Larr, yw16, zxb, rms_w, Gb);
    k_gemm<0><<<dim3(NTOK/128, DMODEL/64), 256, 0, stream>>>(Gb, Wto, out, nullptr, DINNER, DMODEL);
}